// Round 13
// baseline (2651.591 us; speedup 1.0000x reference)
//
#include <hip/hip_runtime.h>
#include <hip/hip_bf16.h>

#define DEVI __device__ __forceinline__

typedef __bf16 bfrag __attribute__((ext_vector_type(8)));
typedef unsigned short us8 __attribute__((ext_vector_type(8)));
typedef float f32x4 __attribute__((ext_vector_type(4)));
typedef unsigned short ushort_t;

static constexpr int NB  = 16;
static constexpr int NH  = 8;
static constexpr int DIM = 1024;
static constexpr int DQh = 128;
static constexpr int ST  = 1024;
static constexpr int SM  = 2048;
static constexpr float INV_SCALE = 0.29730177875068026f; // 1 / 128^0.25
static constexpr float LN_EPS = 1e-5f;

DEVI ushort_t f2bf(float f) {
  __hip_bfloat16 h = __float2bfloat16(f);
  return __builtin_bit_cast(ushort_t, h);
}
DEVI float bf2f(ushort_t u) {
  return __bfloat162float(__builtin_bit_cast(__hip_bfloat16, u));
}
DEVI bfrag ldfrag(const ushort_t* p) {
  return __builtin_bit_cast(bfrag, *(const us8*)p);
}
DEVI void gl16(const ushort_t* g, ushort_t* l) {
  __builtin_amdgcn_global_load_lds(
      (const __attribute__((address_space(1))) void*)g,
      (__attribute__((address_space(3))) void*)l, 16, 0, 0);
}

enum { ST_BF16 = 0, ST_SWISH = 1, ST_ABS = 2, ST_YSTAT = 3, ST_ZSTAT = 4,
       ST_ZRES = 5 };

// ---------------------------------------------------------------------------
// K/V projection GEMM with fused wave-local softmax; s-blocked store
// [z][S/8][128 d][8 s] consumed by gemm_ktv. Pure gl16 staging.
// launch_bounds(256,8): 48 VGPR / 16KB LDS permit 8 blocks/CU -> ~100% occ.
// ---------------------------------------------------------------------------
__global__ __launch_bounds__(256, 8)
void gemm_qkv(const ushort_t* __restrict__ A, const ushort_t* __restrict__ Bt,
              ushort_t* __restrict__ P0, ushort_t* __restrict__ P1,
              int M, int N, int K, int logS, int smflags)
{
  __shared__ ushort_t As[128][32];
  __shared__ ushort_t Bs[128][32];
  const int tid = threadIdx.x;
  int bx = blockIdx.x, by = blockIdx.y;
  {
    const int gx = gridDim.x;
    const int nwg = gx * gridDim.y;
    int bid = by * gx + bx;
    if ((nwg & 7) == 0) bid = (bid & 7) * (nwg >> 3) + (bid >> 3);  // XCD swizzle
    bx = bid % gx; by = bid / gx;
  }
  const int m0 = by * 128, n0 = bx * 128;

  const int lane = tid & 63;
  const int w = tid >> 6;
  const int wr = w * 32;
  const int frow = lane & 15;
  const int q = lane >> 4;

  const int grow = lane >> 2;
  const int gk = ((lane & 3) ^ ((lane >> 3) & 3)) * 8;
  const ushort_t* Ag = A + (long)(m0 + w * 32 + grow) * K + gk;
  const ushort_t* Bg = Bt + (long)(n0 + w * 32 + grow) * K + gk;

  f32x4 acc[2][8];
  #pragma unroll
  for (int i = 0; i < 2; ++i)
    #pragma unroll
    for (int j = 0; j < 8; ++j) acc[i][j] = f32x4{0.f, 0.f, 0.f, 0.f};

  const int kqs = (frow >> 1) & 3;
  for (int k0 = 0; k0 < K; k0 += 32) {
    __syncthreads();
    gl16(Ag + k0,                &As[w * 32][0]);
    gl16(Ag + k0 + (long)16 * K, &As[w * 32 + 16][0]);
    gl16(Bg + k0,                &Bs[w * 32][0]);
    gl16(Bg + k0 + (long)16 * K, &Bs[w * 32 + 16][0]);
    __syncthreads();
    const int kq = (q ^ kqs) * 8;
    const bfrag af0 = ldfrag(&As[wr + frow][kq]);
    const bfrag af1 = ldfrag(&As[wr + 16 + frow][kq]);
    #pragma unroll
    for (int j = 0; j < 8; ++j) {
      const bfrag bf = ldfrag(&Bs[j * 16 + frow][kq]);
      acc[0][j] = __builtin_amdgcn_mfma_f32_16x16x32_bf16(af0, bf, acc[0][j], 0, 0, 0);
      acc[1][j] = __builtin_amdgcn_mfma_f32_16x16x32_bf16(af1, bf, acc[1][j], 0, 0, 0);
    }
  }

  const int sel = n0 >> 10;
  const bool dosm = (smflags >> sel) & 1;
  const int h = (n0 >> 7) & 7;
  ushort_t* __restrict__ Bq = (sel == 0) ? P0 : P1;
  const int S = 1 << logS;
  const int b_blk = m0 >> logS;
  const int s_m0 = m0 & (S - 1);

  if (dosm) {
    #pragma unroll
    for (int i = 0; i < 2; ++i) {
      #pragma unroll
      for (int e = 0; e < 4; ++e) {
        float v[8];
        #pragma unroll
        for (int j = 0; j < 8; ++j) v[j] = acc[i][j][e] * INV_SCALE;
        float mx = v[0];
        #pragma unroll
        for (int j = 1; j < 8; ++j) mx = fmaxf(mx, v[j]);
        mx = fmaxf(mx, __shfl_xor(mx, 1));
        mx = fmaxf(mx, __shfl_xor(mx, 2));
        mx = fmaxf(mx, __shfl_xor(mx, 4));
        mx = fmaxf(mx, __shfl_xor(mx, 8));
        float sm = 0.f;
        #pragma unroll
        for (int j = 0; j < 8; ++j) { v[j] = __expf(v[j] - mx); sm += v[j]; }
        sm += __shfl_xor(sm, 1);
        sm += __shfl_xor(sm, 2);
        sm += __shfl_xor(sm, 4);
        sm += __shfl_xor(sm, 8);
        const float inv = 1.0f / sm;
        #pragma unroll
        for (int j = 0; j < 8; ++j) acc[i][j][e] = v[j] * inv;
      }
    }
  }

  ushort_t* zbase = Bq + (long)(h * 16 + b_blk) * S * 128;
  #pragma unroll
  for (int i = 0; i < 2; ++i) {
    const int sb = s_m0 + wr + i * 16 + q * 4;
    ushort_t* rowb = zbase + (long)(sb >> 3) * 1024 + (sb & 7);
    #pragma unroll
    for (int j = 0; j < 8; ++j) {
      ushort4 o = make_ushort4(f2bf(acc[i][j][0]), f2bf(acc[i][j][1]),
                               f2bf(acc[i][j][2]), f2bf(acc[i][j][3]));
      *(ushort4*)(rowb + (j * 16 + frow) * 8) = o;
    }
  }
}

// ---------------------------------------------------------------------------
// Fused Q path: scores -> (optional LN-absorb) -> wave-local softmax -> P@A
// -> scramble store. LDS 48KB caps at 3 blocks/CU.
// ---------------------------------------------------------------------------
template<bool MASKED, bool ABSORB>
__global__ __launch_bounds__(256, 3)
void fused_qa(const ushort_t* __restrict__ A, const ushort_t* __restrict__ Wq,
              const ushort_t* __restrict__ AT, ushort_t* __restrict__ Out,
              const float* __restrict__ SIn, const float* __restrict__ C1,
              const float* __restrict__ C2)
{
  __shared__ ushort_t As[128][32];
  __shared__ ushort_t Bs[128][32];
  __shared__ ushort_t Ps[4][32][128];
  const int tid = threadIdx.x;
  int h = blockIdx.x, by = blockIdx.y;
  {
    const int gx = gridDim.x;
    const int nwg = gx * gridDim.y;
    int bid = by * gx + h;
    if ((nwg & 7) == 0) bid = (bid & 7) * (nwg >> 3) + (bid >> 3);
    h = bid % gx; by = bid / gx;
  }
  const int m0 = by * 128;

  const int lane = tid & 63;
  const int w = tid >> 6;
  const int wr = w * 32;
  const int frow = lane & 15;
  const int q = lane >> 4;

  const int grow = lane >> 2;
  const int gk = ((lane & 3) ^ ((lane >> 3) & 3)) * 8;
  const ushort_t* Ag = A + (long)(m0 + w * 32 + grow) * 1024 + gk;
  const ushort_t* Bg = Wq + (long)(h * 128 + w * 32 + grow) * 1024 + gk;

  f32x4 acc[2][8];
  #pragma unroll
  for (int i = 0; i < 2; ++i)
    #pragma unroll
    for (int j = 0; j < 8; ++j) acc[i][j] = f32x4{0.f, 0.f, 0.f, 0.f};

  const int kqs = (frow >> 1) & 3;
  for (int k0 = 0; k0 < 1024; k0 += 32) {
    __syncthreads();
    gl16(Ag + k0,             &As[w * 32][0]);
    gl16(Ag + k0 + 16 * 1024, &As[w * 32 + 16][0]);
    gl16(Bg + k0,             &Bs[w * 32][0]);
    gl16(Bg + k0 + 16 * 1024, &Bs[w * 32 + 16][0]);
    __syncthreads();
    const int kq = (q ^ kqs) * 8;
    const bfrag af0 = ldfrag(&As[wr + frow][kq]);
    const bfrag af1 = ldfrag(&As[wr + 16 + frow][kq]);
    #pragma unroll
    for (int j = 0; j < 8; ++j) {
      const bfrag bf = ldfrag(&Bs[j * 16 + frow][kq]);
      acc[0][j] = __builtin_amdgcn_mfma_f32_16x16x32_bf16(af0, bf, acc[0][j], 0, 0, 0);
      acc[1][j] = __builtin_amdgcn_mfma_f32_16x16x32_bf16(af1, bf, acc[1][j], 0, 0, 0);
    }
  }

  float c1j[8], c2j[8];
  if (ABSORB) {
    #pragma unroll
    for (int j = 0; j < 8; ++j) {
      c1j[j] = C1[h * 128 + j * 16 + frow];
      c2j[j] = C2[h * 128 + j * 16 + frow];
    }
  }

  #pragma unroll
  for (int i = 0; i < 2; ++i) {
    #pragma unroll
    for (int e = 0; e < 4; ++e) {
      const int row32 = i * 16 + q * 4 + e;
      const int gmr = m0 + wr + row32;
      const int srow = gmr & (ST - 1);
      float v[8];
      #pragma unroll
      for (int j = 0; j < 8; ++j) v[j] = acc[i][j][e];
      if (ABSORB) {
        const float mu = SIn[gmr * 2], rr = SIn[gmr * 2 + 1];
        #pragma unroll
        for (int j = 0; j < 8; ++j)
          v[j] = rr * v[j] - rr * mu * c1j[j] + c2j[j];
      }
      #pragma unroll
      for (int j = 0; j < 8; ++j) {
        v[j] *= INV_SCALE;
        if (MASKED && (j * 16 + frow) > srow) v[j] = -3.0e38f;
      }
      float mx = v[0];
      #pragma unroll
      for (int j = 1; j < 8; ++j) mx = fmaxf(mx, v[j]);
      mx = fmaxf(mx, __shfl_xor(mx, 1));
      mx = fmaxf(mx, __shfl_xor(mx, 2));
      mx = fmaxf(mx, __shfl_xor(mx, 4));
      mx = fmaxf(mx, __shfl_xor(mx, 8));
      float sm = 0.f;
      #pragma unroll
      for (int j = 0; j < 8; ++j) { v[j] = __expf(v[j] - mx); sm += v[j]; }
      sm += __shfl_xor(sm, 1);
      sm += __shfl_xor(sm, 2);
      sm += __shfl_xor(sm, 4);
      sm += __shfl_xor(sm, 8);
      const float inv = 1.0f / sm;
      const int sw = (row32 >> 1) & 3;
      ushort_t* pr = &Ps[w][row32][0];
      #pragma unroll
      for (int j = 0; j < 8; ++j) {
        const int c = j * 16 + frow;
        const int pos = (c & ~31) | ((((c >> 3) & 3) ^ sw) << 3) | (c & 7);
        pr[pos] = f2bf(v[j] * inv);
      }
    }
  }

  f32x4 acc2[2][8];
  #pragma unroll
  for (int i = 0; i < 2; ++i)
    #pragma unroll
    for (int j = 0; j < 8; ++j) acc2[i][j] = f32x4{0.f, 0.f, 0.f, 0.f};

  const ushort_t* Atg = AT + (long)((h << 4) + (m0 >> 10)) * 16384 +
                        (long)(w * 32 + grow) * 128 + gk;
  for (int d0 = 0; d0 < 128; d0 += 32) {
    __syncthreads();
    gl16(Atg + d0,            &Bs[w * 32][0]);
    gl16(Atg + d0 + 16 * 128, &Bs[w * 32 + 16][0]);
    __syncthreads();
    const int kq = (q ^ kqs) * 8;
    const bfrag af0 = ldfrag(&Ps[w][frow][d0 + kq]);
    const bfrag af1 = ldfrag(&Ps[w][16 + frow][d0 + kq]);
    #pragma unroll
    for (int j = 0; j < 8; ++j) {
      const bfrag bf = ldfrag(&Bs[j * 16 + frow][kq]);
      acc2[0][j] = __builtin_amdgcn_mfma_f32_16x16x32_bf16(af0, bf, acc2[0][j], 0, 0, 0);
      acc2[1][j] = __builtin_amdgcn_mfma_f32_16x16x32_bf16(af1, bf, acc2[1][j], 0, 0, 0);
    }
  }

  ushort_t* ob = Out + (long)(m0 >> 10) * (ST * DIM);
  #pragma unroll
  for (int i = 0; i < 2; ++i) {
    #pragma unroll
    for (int e = 0; e < 4; ++e) {
      const int srow = (m0 + wr + i * 16 + q * 4 + e) & (ST - 1);
      ushort_t* orow = ob + (long)(h * 128 + (srow >> 3)) * DIM + (srow & 7) * 128;
      #pragma unroll
      for (int j = 0; j < 8; ++j)
        orow[j * 16 + frow] = f2bf(acc2[i][j][e]);
    }
  }
}

// ---------------------------------------------------------------------------
// 128x128-tile bf16 GEMM (m97 structure), 2x2 waves. Epilogues as R9.
// launch_bounds(256,3): ~170 VGPR cap, 3 blocks/CU (was 2).
// ---------------------------------------------------------------------------
template<int STORE>
__global__ __launch_bounds__(256, 3)
void gemm_bb(const ushort_t* __restrict__ A, const ushort_t* __restrict__ Bt,
             const float* __restrict__ Res, const float* __restrict__ SIn,
             const float* __restrict__ Gv, const float* __restrict__ Bv,
             const float* __restrict__ C1, const float* __restrict__ C2,
             ushort_t* __restrict__ Pb, float* __restrict__ Cf,
             float* __restrict__ PStat, int M, int N, int K)
{
  __shared__ ushort_t As[128][32];
  __shared__ ushort_t Bs[128][32];
  const int tid = threadIdx.x;
  int bx = blockIdx.x, by = blockIdx.y;
  {
    const int gx = gridDim.x;
    const int nwg = gx * gridDim.y;
    int bid = by * gx + bx;
    if ((nwg & 7) == 0) bid = (bid & 7) * (nwg >> 3) + (bid >> 3);
    bx = bid % gx; by = bid / gx;
  }
  const int m0 = by * 128, n0 = bx * 128;

  const int lane = tid & 63;
  const int w = tid >> 6;
  const int wr = (w >> 1) * 64, wc = (w & 1) * 64;
  const int frow = lane & 15;
  const int q = lane >> 4;

  const int grow = lane >> 2;
  const int gk = ((lane & 3) ^ ((lane >> 3) & 3)) * 8;
  const ushort_t* Ag = A + (long)(m0 + w * 32 + grow) * K + gk;
  const ushort_t* Bg = Bt + (long)(n0 + w * 32 + grow) * K + gk;

  f32x4 acc[4][4];
  #pragma unroll
  for (int i = 0; i < 4; ++i)
    #pragma unroll
    for (int j = 0; j < 4; ++j) acc[i][j] = f32x4{0.f, 0.f, 0.f, 0.f};

  const int kqs = (frow >> 1) & 3;
  for (int k0 = 0; k0 < K; k0 += 32) {
    __syncthreads();
    gl16(Ag + k0,                &As[w * 32][0]);
    gl16(Ag + k0 + (long)16 * K, &As[w * 32 + 16][0]);
    gl16(Bg + k0,                &Bs[w * 32][0]);
    gl16(Bg + k0 + (long)16 * K, &Bs[w * 32 + 16][0]);
    __syncthreads();
    const int kq = (q ^ kqs) * 8;
    bfrag af[4], bf[4];
    #pragma unroll
    for (int i = 0; i < 4; ++i) af[i] = ldfrag(&As[wr + i * 16 + frow][kq]);
    #pragma unroll
    for (int j = 0; j < 4; ++j) bf[j] = ldfrag(&Bs[wc + j * 16 + frow][kq]);
    #pragma unroll
    for (int i = 0; i < 4; ++i)
      #pragma unroll
      for (int j = 0; j < 4; ++j)
        acc[i][j] = __builtin_amdgcn_mfma_f32_16x16x32_bf16(af[i], bf[j], acc[i][j], 0, 0, 0);
  }

  const int rb = q * 4;
  if constexpr (STORE == ST_YSTAT || STORE == ST_ZSTAT) {
    float gvj[4], bvj[4];
    if constexpr (STORE == ST_ZSTAT) {
      #pragma unroll
      for (int j = 0; j < 4; ++j) {
        gvj[j] = Gv[n0 + wc + j * 16 + frow];
        bvj[j] = Bv[n0 + wc + j * 16 + frow];
      }
    }
    #pragma unroll
    for (int i = 0; i < 4; ++i) {
      #pragma unroll
      for (int e = 0; e < 4; ++e) {
        const int gm = m0 + wr + i * 16 + rb + e;
        float mu = 0.f, rr = 0.f;
        if constexpr (STORE == ST_ZSTAT) { mu = SIn[gm * 2]; rr = SIn[gm * 2 + 1]; }
        float s = 0.f, sq = 0.f, vals[4];
        #pragma unroll
        for (int j = 0; j < 4; ++j) {
          const int gn = n0 + wc + j * 16 + frow;
          float rv = Res[(long)gm * N + gn];
          if constexpr (STORE == ST_ZSTAT) rv = (rv - mu) * rr * gvj[j] + bvj[j];
          const float v = acc[i][j][e] + rv;
          vals[j] = v; s += v; sq += v * v;
        }
        #pragma unroll
        for (int j = 0; j < 4; ++j) {
          const int gn = n0 + wc + j * 16 + frow;
          Cf[(long)gm * N + gn] = vals[j];
          Pb[(long)gm * N + gn] = f2bf(vals[j]);
        }
        s += __shfl_xor(s, 1);  sq += __shfl_xor(sq, 1);
        s += __shfl_xor(s, 2);  sq += __shfl_xor(sq, 2);
        s += __shfl_xor(s, 4);  sq += __shfl_xor(sq, 4);
        s += __shfl_xor(s, 8);  sq += __shfl_xor(sq, 8);
        if (frow == 0) {
          const int p = (n0 >> 7) * 2 + (wc >> 6);
          PStat[((long)gm * 16 + p) * 2]     = s;
          PStat[((long)gm * 16 + p) * 2 + 1] = sq;
        }
      }
    }
  } else if constexpr (STORE == ST_ABS) {
    float c1j[4], c2j[4];
    #pragma unroll
    for (int j = 0; j < 4; ++j) {
      c1j[j] = C1[n0 + wc + j * 16 + frow];
      c2j[j] = C2[n0 + wc + j * 16 + frow];
    }
    #pragma unroll
    for (int i = 0; i < 4; ++i) {
      #pragma unroll
      for (int e = 0; e < 4; ++e) {
        const int gm = m0 + wr + i * 16 + rb + e;
        const float mu = SIn[gm * 2], rr = SIn[gm * 2 + 1];
        #pragma unroll
        for (int j = 0; j < 4; ++j) {
          const int gn = n0 + wc + j * 16 + frow;
          const float v = rr * acc[i][j][e] - rr * mu * c1j[j] + c2j[j];
          Pb[(long)gm * N + gn] = f2bf(v);
        }
      }
    }
  } else if constexpr (STORE == ST_ZRES) {
    float gvj[4], bvj[4];
    #pragma unroll
    for (int j = 0; j < 4; ++j) {
      gvj[j] = Gv[n0 + wc + j * 16 + frow];
      bvj[j] = Bv[n0 + wc + j * 16 + frow];
    }
    #pragma unroll
    for (int i = 0; i < 4; ++i) {
      #pragma unroll
      for (int e = 0; e < 4; ++e) {
        const int gm = m0 + wr + i * 16 + rb + e;
        const float mu = SIn[gm * 2], rr = SIn[gm * 2 + 1];
        #pragma unroll
        for (int j = 0; j < 4; ++j) {
          const int gn = n0 + wc + j * 16 + frow;
          const float rv = Res[(long)gm * N + gn];
          const float z = (rv - mu) * rr * gvj[j] + bvj[j];
          Cf[(long)gm * N + gn] = acc[i][j][e] + z;
        }
      }
    }
  } else {
    #pragma unroll
    for (int i = 0; i < 4; ++i) {
      #pragma unroll
      for (int j = 0; j < 4; ++j) {
        #pragma unroll
        for (int e = 0; e < 4; ++e) {
          const int gm = m0 + wr + i * 16 + rb + e;
          const int gn = n0 + wc + j * 16 + frow;
          float val = acc[i][j][e];
          if constexpr (STORE == ST_SWISH) val = val / (1.0f + __expf(-val));
          Pb[(long)gm * N + gn] = f2bf(val);
        }
      }
    }
  }
}

// partial stats [M][16][2] -> per-row (mu, rstd)
__global__ __launch_bounds__(256)
void stats_reduce(const float* __restrict__ PS, float* __restrict__ SO)
{
  const int row = blockIdx.x * 256 + threadIdx.x;
  float s = 0.f, sq = 0.f;
  const float* p = PS + (long)row * 32;
  #pragma unroll
  for (int k = 0; k < 16; ++k) { s += p[2 * k]; sq += p[2 * k + 1]; }
  const float mu = s * (1.0f / 1024.0f);
  const float var = sq * (1.0f / 1024.0f) - mu * mu;
  SO[row * 2] = mu;
  SO[row * 2 + 1] = rsqrtf(var + LN_EPS);
}

// ---------------------------------------------------------------------------
// Merged c-vector kernel.
// ---------------------------------------------------------------------------
DEVI void cvec_body(const float* W, const float* g, const float* b,
                    float* c1, float* c2, int n, int lane,
                    long hstride, int nb_h, int nstride, int kstride, int K)
{
  const long base = (long)(n / nb_h) * hstride + (long)(n % nb_h) * nstride;
  float s1 = 0.f, s2 = 0.f;
  for (int k = lane; k < K; k += 64) {
    const float wv = W[base + (long)k * kstride];
    s1 += g[k] * wv; s2 += b[k] * wv;
  }
  #pragma unroll
  for (int o = 32; o; o >>= 1) { s1 += __shfl_xor(s1, o); s2 += __shfl_xor(s2, o); }
  if (lane == 0) { c1[n] = s1; c2[n] = s2; }
}

__global__ __launch_bounds__(256)
void cvec2(const float* __restrict__ Wq2, const float* __restrict__ g1,
           const float* __restrict__ b1, float* __restrict__ c1q,
           float* __restrict__ c2q,
           const float* __restrict__ E1, const float* __restrict__ g2,
           const float* __restrict__ b2, float* __restrict__ c1e,
           float* __restrict__ c2e)
{
  const int lane = threadIdx.x & 63;
  if (blockIdx.x < 256) {
    const int n = (blockIdx.x * 256 + threadIdx.x) >> 6;
    cvec_body(Wq2, g1, b1, c1q, c2q, n, lane, (long)DIM * DQh, 128, 1, 128, 1024);
  } else {
    const int n = ((blockIdx.x - 256) * 256 + threadIdx.x) >> 6;
    cvec_body(E1, g2, b2, c1e, c2e, n, lane, 0, 512, 1024, 1, 1024);
  }
}

// ---------------------------------------------------------------------------
// Split-S K^T·V from the s-blocked layout; bf16 partials.
// ---------------------------------------------------------------------------
__global__ __launch_bounds__(256, 4)
void gemm_ktv(const ushort_t* __restrict__ Kp, const ushort_t* __restrict__ Vp,
              ushort_t* __restrict__ P, int S, int SC)
{
  __shared__ ushort_t As[4096];
  __shared__ ushort_t Bs[4096];
  const int tid = threadIdx.x;
  const int z = blockIdx.x;
  const int ch = blockIdx.y;
  const int lane = tid & 63, w = tid >> 6;
  const int wr = (w >> 1) * 64, wc = (w & 1) * 64;
  const int frow = lane & 15, q = lane >> 4;
  const long zoff = (long)z * S * 128 + ((long)(ch * SC) >> 3) * 1024;
  const ushort_t* Vg = Vp + zoff + lane * 8;
  const ushort_t* Kg = Kp + zoff + lane * 8;

  f32x4 acc[4][4];
  #pragma unroll
  for (int i = 0; i < 4; ++i)
    #pragma unroll
    for (int j = 0; j < 4; ++j) acc[i][j] = f32x4{0.f, 0.f, 0.f, 0.f};

  for (int s0 = 0; s0 < SC; s0 += 32) {
    const long go = ((long)s0 >> 3) * 1024;
    __syncthreads();
    gl16(Vg + go + (2 * w) * 512,     &As[(2 * w) * 512]);
    gl16(Vg + go + (2 * w + 1) * 512, &As[(2 * w + 1) * 512]);
    gl16(Kg + go + (2 * w) * 512,     &Bs[(2 * w) * 512]);
    gl16(Kg + go + (2 * w + 1) * 512, &Bs[(2 * w + 1) * 512]);
    __syncthreads();
    bfrag af[4], bf[4];
    #pragma unroll
    for (int i = 0; i < 4; ++i)
      af[i] = ldfrag(&As[q * 1024 + (wr + i * 16 + frow) * 8]);
    #pragma unroll
    for (int j = 0; j < 4; ++j)
      bf[j] = ldfrag(&Bs[q * 1024 + (wc + j * 16 + frow) * 8]);
    #pragma unroll
    for (int i = 0; i < 4; ++i)
      #pragma unroll
      for (int j = 0; j < 4; ++j)
        acc[i][j] = __builtin_amdgcn_mfma_f32_16x16x32_bf16(af[i], bf[j], acc[i][j], 0, 0, 0);
  }
  ushort_t* Pz = P + ((long)ch * 128 + z) * 16384;
  const int rb = q * 4;
  #pragma unroll
  for (int i = 0; i < 4; ++i)
    #pragma unroll
    for (int j = 0; j < 4; ++j)
      #pragma unroll
      for (int e = 0; e < 4; ++e)
        Pz[(long)(wr + i * 16 + rb + e) * 128 + (wc + j * 16 + frow)] =
            f2bf(acc[i][j][e]);
}

// sum bf16 partials over chunks -> bf16 AT.
__global__ __launch_bounds__(256)
void ktv_reduce(const ushort_t* __restrict__ P, ushort_t* __restrict__ AT, int nch)
{
  const long i = ((long)blockIdx.x * 256 + threadIdx.x) * 8;
  float s[8] = {0.f, 0.f, 0.f, 0.f, 0.f, 0.f, 0.f, 0.f};
  for (int c = 0; c < nch; ++c) {
    const us8 v = *(const us8*)(P + (long)c * 2097152 + i);
    #pragma unroll
    for (int k = 0; k < 8; ++k) s[k] += bf2f(v[k]);
  }
  us8 o;
  #pragma unroll
  for (int k = 0; k < 8; ++k) o[k] = f2bf(s[k]);
  *(us8*)(AT + i) = o;
}

// ---------------------------------------------------------------------------
// LayerNorm (final stage only), f32 in -> f32 out.
// ---------------------------------------------------------------------------
__global__ __launch_bounds__(256)
void layernorm_k(const float* __restrict__ X, const float* __restrict__ G,
                 const float* __restrict__ Bta, float* __restrict__ Y)
{
  const int row = blockIdx.x;
  const int t = threadIdx.x;
  const float4 v = *(const float4*)(X + (long)row * DIM + t * 4);
  float s  = v.x + v.y + v.z + v.w;
  float sq = v.x * v.x + v.y * v.y + v.z * v.z + v.w * v.w;
  #pragma unroll
  for (int o = 32; o; o >>= 1) { s += __shfl_xor(s, o); sq += __shfl_xor(sq, o); }
  __shared__ float ps[4], pq[4];
  if ((t & 63) == 0) { ps[t >> 6] = s; pq[t >> 6] = sq; }
  __syncthreads();
  s  = ps[0] + ps[1] + ps[2] + ps[3];
  sq = pq[0] + pq[1] + pq[2] + pq[3];
  const float mean = s * (1.0f / DIM);
  const float var  = sq * (1.0f / DIM) - mean * mean;
  const float rstd = rsqrtf(var + LN_EPS);
  const float4 gv = *(const float4*)(G + t * 4);
  const float4 bv = *(const float4*)(Bta + t * 4);
  float4 o;
  o.x = (v.x - mean) * rstd * gv.x + bv.x;
  o.y = (v.y - mean) * rstd * gv.y + bv.y;
  o.z = (v.z - mean) * rstd * gv.z + bv.z;
  o.w = (v.w - mean) * rstd * gv.w + bv.w;
  *(float4*)(Y + (long)row * DIM + t * 4) = o;
}

// ---------------------------------------------------------------------------
// Merged weight transpose: 6 tasks x 8 heads; task 5 (Wq2) scaled by g1[k].
// ---------------------------------------------------------------------------
struct TPack {
  const float* src[6];
  ushort_t* dst[6];
};

__global__ __launch_bounds__(256)
void transpose_all(TPack p, const float* __restrict__ g1)
{
  __shared__ float tile[32][33];
  const int task = blockIdx.z >> 3;
  const int z = blockIdx.z & 7;
  const int kb = blockIdx.y * 32;
  const int nb = blockIdx.x * 32;
  const float* src = p.src[task] + (long)z * DIM * DQh;
  ushort_t* dst = p.dst[task] + (long)z * DIM * DQh;
  const int tx = threadIdx.x & 31;
  const int ty = threadIdx.x >> 5;
  #pragma unroll
  for (int r = 0; r < 32; r += 8)
    tile[ty + r][tx] = src[(long)(kb + ty + r) * DQh + nb + tx];
  __syncthreads();
  const float gs = (task == 5) ? g1[kb + tx] : 1.0f;
  #pragma unroll
  for (int r = 0; r < 32; r += 8)
    dst[(long)(nb + ty + r) * DIM + kb + tx] = f2bf(tile[tx][ty + r] * gs);
}

// ---------------------------------------------------------------------------
// Merged elementwise casts: 8 tasks; task 4 (E1) scaled by g2[k].
// ---------------------------------------------------------------------------
struct CPack {
  const float* src[8];
  ushort_t* dst[8];
  const float* g2;
};

__global__ __launch_bounds__(256)
void cast_all(CPack p)
{
  const int bid = blockIdx.x;
  int t;
  long base;
  if      (bid < 16384) { t = 0; base = 0; }
  else if (bid < 49152) { t = 1; base = 16384; }
  else if (bid < 50176) { t = 2; base = 49152; }
  else if (bid < 51200) { t = 3; base = 50176; }
  else if (bid < 51712) { t = 4; base = 51200; }
  else if (bid < 52224) { t = 5; base = 51712; }
  else if (bid < 52736) { t = 6; base = 52224; }
  else                  { t = 7; base = 52736; }
  const long i = ((long)(bid - base) * 256 + threadIdx.x) * 4;
  const float4 v = *(const float4*)(p.src[t] + i);
  float4 o = v;
  if (t == 4) {
    const float4 gv = *(const float4*)(p.g2 + (i & 1023));
    o.x *= gv.x; o.y *= gv.y; o.z *= gv.z; o.w *= gv.w;
  }
  ushort4 sv = make_ushort4(f2bf(o.x), f2bf(o.y), f2bf(o.z), f2bf(o.w));
  *(ushort4*)(p.dst[t] + i) = sv;
}

// ---------------------------------------------------------------------------

extern "C" void kernel_launch(void* const* d_in, const int* in_sizes, int n_in,
                              void* d_out, int out_size, void* d_ws, size_t ws_size,
                              hipStream_t stream)
{
  (void)in_sizes; (void)n_in; (void)out_size; (void)ws_size;
  const float* mem = (const float*)d_in[0];
  const float* y0  = (const float*)d_in[1];
  const float* Wq1 = (const float*)d_in[2];
  const float* Wk1 = (const float*)d_in[3];
  const float* Wv1 = (const float*)d_in[4];
  const float* Wo1 = (const float*)d_in[5];
  const float* Wq2 = (const float*)d_in[6];
  const float* Wk2 = (const float*)d_in[7];
  const float* Wv2 = (const float*)d_in[8];
  const float* Wo2 = (const float*)d_in[9];
  const float* E1  = (const float*)d_in[10];
  const float* D1  = (const float*)d_in[11];
  const float* E2  = (const float*)d_in[12];
  const float* D2  = (const float*)d_in[13];
  const float* g1  = (const float*)d_in[14];
  const float* b1  = (const float*)d_in[15];
  const float* g2  = (const float*)d_in[16];
  const float* b2  = (const float*)d_in[17];
  const float* g3  = (const float*)d_in[18];
  const float* b3  = (const float*)d_in[19];

  char* ws = (char*)d_ws;
  const size_t MB = 1ull << 20;
  ushort_t* wkv1  = (ushort_t*)(ws + 0 * MB);
  ushort_t* wq1t  = (ushort_t*)(ws + 4 * MB);
  ushort_t* wkv2  = (ushort_t*)(ws + 6 * MB);
  ushort_t* wq2t  = (ushort_t*)(ws + 10 * MB);   // g1-scaled
  ushort_t* wo1b  = (ushort_t*)(ws + 12 * MB);
  ushort_t* wo2b  = (ushort_t*)(ws + 14 * MB);
  ushort_t* e1b   = (ushort_t*)(ws + 16 * MB);   // g2-scaled
  ushort_t* d1b   = (ushort_t*)(ws + 17 * MB);
  ushort_t* e2b   = (ushort_t*)(ws + 18 * MB);
  ushort_t* d2b   = (ushort_t*)(ws + 19 * MB);
  ushort_t* y0b   = (ushort_t*)(ws + 20 * MB);   // 32 MB
  ushort_t* memb  = (ushort_t*)(ws + 52 * MB);   // 64 MB
  ushort_t* bn2   = (ushort_t*)(ws + 116 * MB);  // 16 MB
  float*    pstat1 = (float*)(ws + 132 * MB);    // 2 MB
  float*    pstat2 = (float*)(ws + 134 * MB);    // 2 MB
  float*    stats1 = (float*)(ws + 136 * MB);    // 128 KB
  float*    stats2 = (float*)(ws + 137 * MB);    // 128 KB
  float*    c1q    = (float*)(ws + 138 * MB);
  float*    c2q    = (float*)(ws + 139 * MB);
  float*    c1e    = (float*)(ws + 140 * MB);
  float*    c2e    = (float*)(ws + 141 * MB);
  ushort_t* kbuf  = (ushort_t*)(ws + 148 * MB);  // 64 MB (s-blocked)
  ushort_t* vbuf  = (ushort_t*)(ws + 212 * MB);  // 64 MB (s-blocked)
  ushort_t* amatT = (ushort_t*)(ws + 276 * MB);  // 4 MB
  ushort_t* attnb = (ushort_t*)(ws + 280 * MB);  // 32 MB
  float*    ybuf  = (float*)(ws + 312 * MB);     // 64 MB (f32 y-chain)
  ushort_t* ybf   = (ushort_t*)(ws + 376 * MB);  // 32 MB (bf16 y)
  ushort_t* hbuf  = (ushort_t*)(ws + 408 * MB);  // 32 MB
  ushort_t* pbuf  = (ushort_t*)(ws + 440 * MB);  // 16 MB (bf16 ktv partials)
  ushort_t* bn1   = attnb;                       // reuse

  // ---- prep (3 dispatches) ----
  CPack cp;
  cp.src[0] = y0;  cp.dst[0] = y0b;
  cp.src[1] = mem; cp.dst[1] = memb;
  cp.src[2] = Wo1; cp.dst[2] = wo1b;
  cp.src[3] = Wo2; cp.dst[3] = wo2b;
  cp.src[4] = E1;  cp.dst[4] = e1b;
  cp.src[5] = D1;  cp.dst[5] = d1b;
  cp.src[6] = E2;  cp.dst[6] = e2b;
  cp.src[7] = D2;  cp.dst[7] = d2b;
  cp.g2 = g2;
  cast_all<<<53248, 256, 0, stream>>>(cp);

  TPack tp;
  tp.src[0] = Wk1; tp.dst[0] = wkv1;
  tp.src[1] = Wv1; tp.dst[1] = wkv1 + (1 << 20);
  tp.src[2] = Wq1; tp.dst[2] = wq1t;
  tp.src[3] = Wk2; tp.dst[3] = wkv2;
  tp.src[4] = Wv2; tp.dst[4] = wkv2 + (1 << 20);
  tp.src[5] = Wq2; tp.dst[5] = wq2t;
  transpose_all<<<dim3(4, 32, 48), 256, 0, stream>>>(tp, g1);

  cvec2<<<384, 256, 0, stream>>>(Wq2, g1, b1, c1q, c2q, E1, g2, b2, c1e, c2e);

  // ---- phase 1: masked self linear-attention ----
  gemm_qkv<<<dim3(16, 128), 256, 0, stream>>>(
      y0b, wkv1, kbuf, vbuf, NB * ST, 2048, DIM, 10, 0b01);
  gemm_ktv<<<dim3(128, 4), 256, 0, stream>>>(kbuf, vbuf, pbuf, ST, 256);
  ktv_reduce<<<1024, 256, 0, stream>>>(pbuf, amatT, 4);
  fused_qa<true, false><<<dim3(8, 128), 256, 0, stream>>>(
      y0b, wq1t, amatT, attnb, nullptr, nullptr, nullptr);
  gemm_bb<ST_YSTAT><<<dim3(8, 128), 256, 0, stream>>>(
      attnb, wo1b, y0, nullptr, nullptr, nullptr, nullptr, nullptr,
      ybf, ybuf, pstat1, NB * ST, DIM, DIM);
  stats_reduce<<<64, 256, 0, stream>>>(pstat1, stats1);

  // ---- phase 2: cross linear-attention ----
  gemm_qkv<<<dim3(16, 256), 256, 0, stream>>>(
      memb, wkv2, kbuf, vbuf, NB * SM, 2048, DIM, 11, 0b01);
  gemm_ktv<<<dim3(128, 4), 256, 0, stream>>>(kbuf, vbuf, pbuf, SM, 512);
  ktv_reduce<<<1024, 256, 0, stream>>>(pbuf, amatT, 4);
  fused_qa<false, true><<<dim3(8, 128), 256, 0, stream>>>(
      ybf, wq2t, amatT, attnb, stats1, c1q, c2q);
  gemm_bb<ST_ZSTAT><<<dim3(8, 128), 256, 0, stream>>>(
      attnb, wo2b, ybuf, stats1, g1, b1, nullptr, nullptr,
      ybf, ybuf, pstat2, NB * ST, DIM, DIM);
  stats_reduce<<<64, 256, 0, stream>>>(pstat2, stats2);

  // ---- phase 3: LFFN ----
  gemm_bb<ST_ABS><<<dim3(4, 128), 256, 0, stream>>>(
      ybf, e1b, nullptr, stats2, nullptr, nullptr, c1e, c2e,
      bn1, nullptr, nullptr, NB * ST, 512, DIM);
  gemm_bb<ST_SWISH><<<dim3(8, 128), 256, 0, stream>>>(
      bn1, d1b, nullptr, nullptr, nullptr, nullptr, nullptr, nullptr,
      hbuf, nullptr, nullptr, NB * ST, DIM, 512);
  gemm_bb<ST_BF16><<<dim3(4, 128), 256, 0, stream>>>(
      hbuf, e2b, nullptr, nullptr, nullptr, nullptr, nullptr, nullptr,
      bn2, nullptr, nullptr, NB * ST, 512, DIM);
  gemm_bb<ST_ZRES><<<dim3(8, 128), 256, 0, stream>>>(
      bn2, d2b, ybuf, stats2, g2, b2, nullptr, nullptr,
      nullptr, ybuf, nullptr, NB * ST, DIM, 512);
  layernorm_k<<<NB * ST, 256, 0, stream>>>(ybuf, g3, b3, (float*)d_out);
}

// Round 14
// 1566.614 us; speedup vs baseline: 1.6926x; 1.6926x over previous
//
#include <hip/hip_runtime.h>
#include <hip/hip_bf16.h>

#define DEVI __device__ __forceinline__

typedef __bf16 bfrag __attribute__((ext_vector_type(8)));
typedef unsigned short us8 __attribute__((ext_vector_type(8)));
typedef float f32x4 __attribute__((ext_vector_type(4)));
typedef unsigned short ushort_t;

static constexpr int NB  = 16;
static constexpr int NH  = 8;
static constexpr int DIM = 1024;
static constexpr int DQh = 128;
static constexpr int ST  = 1024;
static constexpr int SM  = 2048;
static constexpr float INV_SCALE = 0.29730177875068026f; // 1 / 128^0.25
static constexpr float LN_EPS = 1e-5f;

DEVI ushort_t f2bf(float f) {
  __hip_bfloat16 h = __float2bfloat16(f);
  return __builtin_bit_cast(ushort_t, h);
}
DEVI float bf2f(ushort_t u) {
  return __bfloat162float(__builtin_bit_cast(__hip_bfloat16, u));
}
DEVI bfrag ldfrag(const ushort_t* p) {
  return __builtin_bit_cast(bfrag, *(const us8*)p);
}
DEVI void gl16(const ushort_t* g, ushort_t* l) {
  __builtin_amdgcn_global_load_lds(
      (const __attribute__((address_space(1))) void*)g,
      (__attribute__((address_space(3))) void*)l, 16, 0, 0);
}

enum { ST_BF16 = 0, ST_SWISH = 1, ST_ABS = 2, ST_YSTAT = 3, ST_ZSTAT = 4,
       ST_ZRES = 5 };

// ---------------------------------------------------------------------------
// K/V projection GEMM with fused wave-local softmax; s-blocked store
// [z][S/8][128 d][8 s] consumed by gemm_ktv. Pure gl16 staging.
// launch_bounds(256,6): VGPR cap ~85 >= the 48 used (NO spill; (256,8)'s
// 64-cap forced spill-to-scratch, R13 disaster). 6 blocks/CU vs 4.
// ---------------------------------------------------------------------------
__global__ __launch_bounds__(256, 6)
void gemm_qkv(const ushort_t* __restrict__ A, const ushort_t* __restrict__ Bt,
              ushort_t* __restrict__ P0, ushort_t* __restrict__ P1,
              int M, int N, int K, int logS, int smflags)
{
  __shared__ ushort_t As[128][32];
  __shared__ ushort_t Bs[128][32];
  const int tid = threadIdx.x;
  int bx = blockIdx.x, by = blockIdx.y;
  {
    const int gx = gridDim.x;
    const int nwg = gx * gridDim.y;
    int bid = by * gx + bx;
    if ((nwg & 7) == 0) bid = (bid & 7) * (nwg >> 3) + (bid >> 3);  // XCD swizzle
    bx = bid % gx; by = bid / gx;
  }
  const int m0 = by * 128, n0 = bx * 128;

  const int lane = tid & 63;
  const int w = tid >> 6;
  const int wr = w * 32;
  const int frow = lane & 15;
  const int q = lane >> 4;

  const int grow = lane >> 2;
  const int gk = ((lane & 3) ^ ((lane >> 3) & 3)) * 8;
  const ushort_t* Ag = A + (long)(m0 + w * 32 + grow) * K + gk;
  const ushort_t* Bg = Bt + (long)(n0 + w * 32 + grow) * K + gk;

  f32x4 acc[2][8];
  #pragma unroll
  for (int i = 0; i < 2; ++i)
    #pragma unroll
    for (int j = 0; j < 8; ++j) acc[i][j] = f32x4{0.f, 0.f, 0.f, 0.f};

  const int kqs = (frow >> 1) & 3;
  for (int k0 = 0; k0 < K; k0 += 32) {
    __syncthreads();
    gl16(Ag + k0,                &As[w * 32][0]);
    gl16(Ag + k0 + (long)16 * K, &As[w * 32 + 16][0]);
    gl16(Bg + k0,                &Bs[w * 32][0]);
    gl16(Bg + k0 + (long)16 * K, &Bs[w * 32 + 16][0]);
    __syncthreads();
    const int kq = (q ^ kqs) * 8;
    const bfrag af0 = ldfrag(&As[wr + frow][kq]);
    const bfrag af1 = ldfrag(&As[wr + 16 + frow][kq]);
    #pragma unroll
    for (int j = 0; j < 8; ++j) {
      const bfrag bf = ldfrag(&Bs[j * 16 + frow][kq]);
      acc[0][j] = __builtin_amdgcn_mfma_f32_16x16x32_bf16(af0, bf, acc[0][j], 0, 0, 0);
      acc[1][j] = __builtin_amdgcn_mfma_f32_16x16x32_bf16(af1, bf, acc[1][j], 0, 0, 0);
    }
  }

  const int sel = n0 >> 10;
  const bool dosm = (smflags >> sel) & 1;
  const int h = (n0 >> 7) & 7;
  ushort_t* __restrict__ Bq = (sel == 0) ? P0 : P1;
  const int S = 1 << logS;
  const int b_blk = m0 >> logS;
  const int s_m0 = m0 & (S - 1);

  if (dosm) {
    #pragma unroll
    for (int i = 0; i < 2; ++i) {
      #pragma unroll
      for (int e = 0; e < 4; ++e) {
        float v[8];
        #pragma unroll
        for (int j = 0; j < 8; ++j) v[j] = acc[i][j][e] * INV_SCALE;
        float mx = v[0];
        #pragma unroll
        for (int j = 1; j < 8; ++j) mx = fmaxf(mx, v[j]);
        mx = fmaxf(mx, __shfl_xor(mx, 1));
        mx = fmaxf(mx, __shfl_xor(mx, 2));
        mx = fmaxf(mx, __shfl_xor(mx, 4));
        mx = fmaxf(mx, __shfl_xor(mx, 8));
        float sm = 0.f;
        #pragma unroll
        for (int j = 0; j < 8; ++j) { v[j] = __expf(v[j] - mx); sm += v[j]; }
        sm += __shfl_xor(sm, 1);
        sm += __shfl_xor(sm, 2);
        sm += __shfl_xor(sm, 4);
        sm += __shfl_xor(sm, 8);
        const float inv = 1.0f / sm;
        #pragma unroll
        for (int j = 0; j < 8; ++j) acc[i][j][e] = v[j] * inv;
      }
    }
  }

  ushort_t* zbase = Bq + (long)(h * 16 + b_blk) * S * 128;
  #pragma unroll
  for (int i = 0; i < 2; ++i) {
    const int sb = s_m0 + wr + i * 16 + q * 4;
    ushort_t* rowb = zbase + (long)(sb >> 3) * 1024 + (sb & 7);
    #pragma unroll
    for (int j = 0; j < 8; ++j) {
      ushort4 o = make_ushort4(f2bf(acc[i][j][0]), f2bf(acc[i][j][1]),
                               f2bf(acc[i][j][2]), f2bf(acc[i][j][3]));
      *(ushort4*)(rowb + (j * 16 + frow) * 8) = o;
    }
  }
}

// ---------------------------------------------------------------------------
// Fused Q path: scores -> (optional LN-absorb) -> wave-local softmax -> P@A
// -> scramble store. LDS 48KB caps at 3 blocks/CU.
// ---------------------------------------------------------------------------
template<bool MASKED, bool ABSORB>
__global__ __launch_bounds__(256, 3)
void fused_qa(const ushort_t* __restrict__ A, const ushort_t* __restrict__ Wq,
              const ushort_t* __restrict__ AT, ushort_t* __restrict__ Out,
              const float* __restrict__ SIn, const float* __restrict__ C1,
              const float* __restrict__ C2)
{
  __shared__ ushort_t As[128][32];
  __shared__ ushort_t Bs[128][32];
  __shared__ ushort_t Ps[4][32][128];
  const int tid = threadIdx.x;
  int h = blockIdx.x, by = blockIdx.y;
  {
    const int gx = gridDim.x;
    const int nwg = gx * gridDim.y;
    int bid = by * gx + h;
    if ((nwg & 7) == 0) bid = (bid & 7) * (nwg >> 3) + (bid >> 3);
    h = bid % gx; by = bid / gx;
  }
  const int m0 = by * 128;

  const int lane = tid & 63;
  const int w = tid >> 6;
  const int wr = w * 32;
  const int frow = lane & 15;
  const int q = lane >> 4;

  const int grow = lane >> 2;
  const int gk = ((lane & 3) ^ ((lane >> 3) & 3)) * 8;
  const ushort_t* Ag = A + (long)(m0 + w * 32 + grow) * 1024 + gk;
  const ushort_t* Bg = Wq + (long)(h * 128 + w * 32 + grow) * 1024 + gk;

  f32x4 acc[2][8];
  #pragma unroll
  for (int i = 0; i < 2; ++i)
    #pragma unroll
    for (int j = 0; j < 8; ++j) acc[i][j] = f32x4{0.f, 0.f, 0.f, 0.f};

  const int kqs = (frow >> 1) & 3;
  for (int k0 = 0; k0 < 1024; k0 += 32) {
    __syncthreads();
    gl16(Ag + k0,             &As[w * 32][0]);
    gl16(Ag + k0 + 16 * 1024, &As[w * 32 + 16][0]);
    gl16(Bg + k0,             &Bs[w * 32][0]);
    gl16(Bg + k0 + 16 * 1024, &Bs[w * 32 + 16][0]);
    __syncthreads();
    const int kq = (q ^ kqs) * 8;
    const bfrag af0 = ldfrag(&As[wr + frow][kq]);
    const bfrag af1 = ldfrag(&As[wr + 16 + frow][kq]);
    #pragma unroll
    for (int j = 0; j < 8; ++j) {
      const bfrag bf = ldfrag(&Bs[j * 16 + frow][kq]);
      acc[0][j] = __builtin_amdgcn_mfma_f32_16x16x32_bf16(af0, bf, acc[0][j], 0, 0, 0);
      acc[1][j] = __builtin_amdgcn_mfma_f32_16x16x32_bf16(af1, bf, acc[1][j], 0, 0, 0);
    }
  }

  float c1j[8], c2j[8];
  if (ABSORB) {
    #pragma unroll
    for (int j = 0; j < 8; ++j) {
      c1j[j] = C1[h * 128 + j * 16 + frow];
      c2j[j] = C2[h * 128 + j * 16 + frow];
    }
  }

  #pragma unroll
  for (int i = 0; i < 2; ++i) {
    #pragma unroll
    for (int e = 0; e < 4; ++e) {
      const int row32 = i * 16 + q * 4 + e;
      const int gmr = m0 + wr + row32;
      const int srow = gmr & (ST - 1);
      float v[8];
      #pragma unroll
      for (int j = 0; j < 8; ++j) v[j] = acc[i][j][e];
      if (ABSORB) {
        const float mu = SIn[gmr * 2], rr = SIn[gmr * 2 + 1];
        #pragma unroll
        for (int j = 0; j < 8; ++j)
          v[j] = rr * v[j] - rr * mu * c1j[j] + c2j[j];
      }
      #pragma unroll
      for (int j = 0; j < 8; ++j) {
        v[j] *= INV_SCALE;
        if (MASKED && (j * 16 + frow) > srow) v[j] = -3.0e38f;
      }
      float mx = v[0];
      #pragma unroll
      for (int j = 1; j < 8; ++j) mx = fmaxf(mx, v[j]);
      mx = fmaxf(mx, __shfl_xor(mx, 1));
      mx = fmaxf(mx, __shfl_xor(mx, 2));
      mx = fmaxf(mx, __shfl_xor(mx, 4));
      mx = fmaxf(mx, __shfl_xor(mx, 8));
      float sm = 0.f;
      #pragma unroll
      for (int j = 0; j < 8; ++j) { v[j] = __expf(v[j] - mx); sm += v[j]; }
      sm += __shfl_xor(sm, 1);
      sm += __shfl_xor(sm, 2);
      sm += __shfl_xor(sm, 4);
      sm += __shfl_xor(sm, 8);
      const float inv = 1.0f / sm;
      const int sw = (row32 >> 1) & 3;
      ushort_t* pr = &Ps[w][row32][0];
      #pragma unroll
      for (int j = 0; j < 8; ++j) {
        const int c = j * 16 + frow;
        const int pos = (c & ~31) | ((((c >> 3) & 3) ^ sw) << 3) | (c & 7);
        pr[pos] = f2bf(v[j] * inv);
      }
    }
  }

  f32x4 acc2[2][8];
  #pragma unroll
  for (int i = 0; i < 2; ++i)
    #pragma unroll
    for (int j = 0; j < 8; ++j) acc2[i][j] = f32x4{0.f, 0.f, 0.f, 0.f};

  const ushort_t* Atg = AT + (long)((h << 4) + (m0 >> 10)) * 16384 +
                        (long)(w * 32 + grow) * 128 + gk;
  for (int d0 = 0; d0 < 128; d0 += 32) {
    __syncthreads();
    gl16(Atg + d0,            &Bs[w * 32][0]);
    gl16(Atg + d0 + 16 * 128, &Bs[w * 32 + 16][0]);
    __syncthreads();
    const int kq = (q ^ kqs) * 8;
    const bfrag af0 = ldfrag(&Ps[w][frow][d0 + kq]);
    const bfrag af1 = ldfrag(&Ps[w][16 + frow][d0 + kq]);
    #pragma unroll
    for (int j = 0; j < 8; ++j) {
      const bfrag bf = ldfrag(&Bs[j * 16 + frow][kq]);
      acc2[0][j] = __builtin_amdgcn_mfma_f32_16x16x32_bf16(af0, bf, acc2[0][j], 0, 0, 0);
      acc2[1][j] = __builtin_amdgcn_mfma_f32_16x16x32_bf16(af1, bf, acc2[1][j], 0, 0, 0);
    }
  }

  ushort_t* ob = Out + (long)(m0 >> 10) * (ST * DIM);
  #pragma unroll
  for (int i = 0; i < 2; ++i) {
    #pragma unroll
    for (int e = 0; e < 4; ++e) {
      const int srow = (m0 + wr + i * 16 + q * 4 + e) & (ST - 1);
      ushort_t* orow = ob + (long)(h * 128 + (srow >> 3)) * DIM + (srow & 7) * 128;
      #pragma unroll
      for (int j = 0; j < 8; ++j)
        orow[j * 16 + frow] = f2bf(acc2[i][j][e]);
    }
  }
}

// ---------------------------------------------------------------------------
// 128x128-tile bf16 GEMM (m97 structure), 2x2 waves. Epilogues as R9.
// launch_bounds(256,2): R12-measured best (bound 3 unverified after R13).
// ---------------------------------------------------------------------------
template<int STORE>
__global__ __launch_bounds__(256, 2)
void gemm_bb(const ushort_t* __restrict__ A, const ushort_t* __restrict__ Bt,
             const float* __restrict__ Res, const float* __restrict__ SIn,
             const float* __restrict__ Gv, const float* __restrict__ Bv,
             const float* __restrict__ C1, const float* __restrict__ C2,
             ushort_t* __restrict__ Pb, float* __restrict__ Cf,
             float* __restrict__ PStat, int M, int N, int K)
{
  __shared__ ushort_t As[128][32];
  __shared__ ushort_t Bs[128][32];
  const int tid = threadIdx.x;
  int bx = blockIdx.x, by = blockIdx.y;
  {
    const int gx = gridDim.x;
    const int nwg = gx * gridDim.y;
    int bid = by * gx + bx;
    if ((nwg & 7) == 0) bid = (bid & 7) * (nwg >> 3) + (bid >> 3);
    bx = bid % gx; by = bid / gx;
  }
  const int m0 = by * 128, n0 = bx * 128;

  const int lane = tid & 63;
  const int w = tid >> 6;
  const int wr = (w >> 1) * 64, wc = (w & 1) * 64;
  const int frow = lane & 15;
  const int q = lane >> 4;

  const int grow = lane >> 2;
  const int gk = ((lane & 3) ^ ((lane >> 3) & 3)) * 8;
  const ushort_t* Ag = A + (long)(m0 + w * 32 + grow) * K + gk;
  const ushort_t* Bg = Bt + (long)(n0 + w * 32 + grow) * K + gk;

  f32x4 acc[4][4];
  #pragma unroll
  for (int i = 0; i < 4; ++i)
    #pragma unroll
    for (int j = 0; j < 4; ++j) acc[i][j] = f32x4{0.f, 0.f, 0.f, 0.f};

  const int kqs = (frow >> 1) & 3;
  for (int k0 = 0; k0 < K; k0 += 32) {
    __syncthreads();
    gl16(Ag + k0,                &As[w * 32][0]);
    gl16(Ag + k0 + (long)16 * K, &As[w * 32 + 16][0]);
    gl16(Bg + k0,                &Bs[w * 32][0]);
    gl16(Bg + k0 + (long)16 * K, &Bs[w * 32 + 16][0]);
    __syncthreads();
    const int kq = (q ^ kqs) * 8;
    bfrag af[4], bf[4];
    #pragma unroll
    for (int i = 0; i < 4; ++i) af[i] = ldfrag(&As[wr + i * 16 + frow][kq]);
    #pragma unroll
    for (int j = 0; j < 4; ++j) bf[j] = ldfrag(&Bs[wc + j * 16 + frow][kq]);
    #pragma unroll
    for (int i = 0; i < 4; ++i)
      #pragma unroll
      for (int j = 0; j < 4; ++j)
        acc[i][j] = __builtin_amdgcn_mfma_f32_16x16x32_bf16(af[i], bf[j], acc[i][j], 0, 0, 0);
  }

  const int rb = q * 4;
  if constexpr (STORE == ST_YSTAT || STORE == ST_ZSTAT) {
    float gvj[4], bvj[4];
    if constexpr (STORE == ST_ZSTAT) {
      #pragma unroll
      for (int j = 0; j < 4; ++j) {
        gvj[j] = Gv[n0 + wc + j * 16 + frow];
        bvj[j] = Bv[n0 + wc + j * 16 + frow];
      }
    }
    #pragma unroll
    for (int i = 0; i < 4; ++i) {
      #pragma unroll
      for (int e = 0; e < 4; ++e) {
        const int gm = m0 + wr + i * 16 + rb + e;
        float mu = 0.f, rr = 0.f;
        if constexpr (STORE == ST_ZSTAT) { mu = SIn[gm * 2]; rr = SIn[gm * 2 + 1]; }
        float s = 0.f, sq = 0.f, vals[4];
        #pragma unroll
        for (int j = 0; j < 4; ++j) {
          const int gn = n0 + wc + j * 16 + frow;
          float rv = Res[(long)gm * N + gn];
          if constexpr (STORE == ST_ZSTAT) rv = (rv - mu) * rr * gvj[j] + bvj[j];
          const float v = acc[i][j][e] + rv;
          vals[j] = v; s += v; sq += v * v;
        }
        #pragma unroll
        for (int j = 0; j < 4; ++j) {
          const int gn = n0 + wc + j * 16 + frow;
          Cf[(long)gm * N + gn] = vals[j];
          Pb[(long)gm * N + gn] = f2bf(vals[j]);
        }
        s += __shfl_xor(s, 1);  sq += __shfl_xor(sq, 1);
        s += __shfl_xor(s, 2);  sq += __shfl_xor(sq, 2);
        s += __shfl_xor(s, 4);  sq += __shfl_xor(sq, 4);
        s += __shfl_xor(s, 8);  sq += __shfl_xor(sq, 8);
        if (frow == 0) {
          const int p = (n0 >> 7) * 2 + (wc >> 6);
          PStat[((long)gm * 16 + p) * 2]     = s;
          PStat[((long)gm * 16 + p) * 2 + 1] = sq;
        }
      }
    }
  } else if constexpr (STORE == ST_ABS) {
    float c1j[4], c2j[4];
    #pragma unroll
    for (int j = 0; j < 4; ++j) {
      c1j[j] = C1[n0 + wc + j * 16 + frow];
      c2j[j] = C2[n0 + wc + j * 16 + frow];
    }
    #pragma unroll
    for (int i = 0; i < 4; ++i) {
      #pragma unroll
      for (int e = 0; e < 4; ++e) {
        const int gm = m0 + wr + i * 16 + rb + e;
        const float mu = SIn[gm * 2], rr = SIn[gm * 2 + 1];
        #pragma unroll
        for (int j = 0; j < 4; ++j) {
          const int gn = n0 + wc + j * 16 + frow;
          const float v = rr * acc[i][j][e] - rr * mu * c1j[j] + c2j[j];
          Pb[(long)gm * N + gn] = f2bf(v);
        }
      }
    }
  } else if constexpr (STORE == ST_ZRES) {
    float gvj[4], bvj[4];
    #pragma unroll
    for (int j = 0; j < 4; ++j) {
      gvj[j] = Gv[n0 + wc + j * 16 + frow];
      bvj[j] = Bv[n0 + wc + j * 16 + frow];
    }
    #pragma unroll
    for (int i = 0; i < 4; ++i) {
      #pragma unroll
      for (int e = 0; e < 4; ++e) {
        const int gm = m0 + wr + i * 16 + rb + e;
        const float mu = SIn[gm * 2], rr = SIn[gm * 2 + 1];
        #pragma unroll
        for (int j = 0; j < 4; ++j) {
          const int gn = n0 + wc + j * 16 + frow;
          const float rv = Res[(long)gm * N + gn];
          const float z = (rv - mu) * rr * gvj[j] + bvj[j];
          Cf[(long)gm * N + gn] = acc[i][j][e] + z;
        }
      }
    }
  } else {
    #pragma unroll
    for (int i = 0; i < 4; ++i) {
      #pragma unroll
      for (int j = 0; j < 4; ++j) {
        #pragma unroll
        for (int e = 0; e < 4; ++e) {
          const int gm = m0 + wr + i * 16 + rb + e;
          const int gn = n0 + wc + j * 16 + frow;
          float val = acc[i][j][e];
          if constexpr (STORE == ST_SWISH) val = val / (1.0f + __expf(-val));
          Pb[(long)gm * N + gn] = f2bf(val);
        }
      }
    }
  }
}

// partial stats [M][16][2] -> per-row (mu, rstd)
__global__ __launch_bounds__(256)
void stats_reduce(const float* __restrict__ PS, float* __restrict__ SO)
{
  const int row = blockIdx.x * 256 + threadIdx.x;
  float s = 0.f, sq = 0.f;
  const float* p = PS + (long)row * 32;
  #pragma unroll
  for (int k = 0; k < 16; ++k) { s += p[2 * k]; sq += p[2 * k + 1]; }
  const float mu = s * (1.0f / 1024.0f);
  const float var = sq * (1.0f / 1024.0f) - mu * mu;
  SO[row * 2] = mu;
  SO[row * 2 + 1] = rsqrtf(var + LN_EPS);
}

// ---------------------------------------------------------------------------
// Merged c-vector kernel.
// ---------------------------------------------------------------------------
DEVI void cvec_body(const float* W, const float* g, const float* b,
                    float* c1, float* c2, int n, int lane,
                    long hstride, int nb_h, int nstride, int kstride, int K)
{
  const long base = (long)(n / nb_h) * hstride + (long)(n % nb_h) * nstride;
  float s1 = 0.f, s2 = 0.f;
  for (int k = lane; k < K; k += 64) {
    const float wv = W[base + (long)k * kstride];
    s1 += g[k] * wv; s2 += b[k] * wv;
  }
  #pragma unroll
  for (int o = 32; o; o >>= 1) { s1 += __shfl_xor(s1, o); s2 += __shfl_xor(s2, o); }
  if (lane == 0) { c1[n] = s1; c2[n] = s2; }
}

__global__ __launch_bounds__(256)
void cvec2(const float* __restrict__ Wq2, const float* __restrict__ g1,
           const float* __restrict__ b1, float* __restrict__ c1q,
           float* __restrict__ c2q,
           const float* __restrict__ E1, const float* __restrict__ g2,
           const float* __restrict__ b2, float* __restrict__ c1e,
           float* __restrict__ c2e)
{
  const int lane = threadIdx.x & 63;
  if (blockIdx.x < 256) {
    const int n = (blockIdx.x * 256 + threadIdx.x) >> 6;
    cvec_body(Wq2, g1, b1, c1q, c2q, n, lane, (long)DIM * DQh, 128, 1, 128, 1024);
  } else {
    const int n = ((blockIdx.x - 256) * 256 + threadIdx.x) >> 6;
    cvec_body(E1, g2, b2, c1e, c2e, n, lane, 0, 512, 1024, 1, 1024);
  }
}

// ---------------------------------------------------------------------------
// Split-S K^T·V from the s-blocked layout; bf16 partials.
// ---------------------------------------------------------------------------
__global__ __launch_bounds__(256, 2)
void gemm_ktv(const ushort_t* __restrict__ Kp, const ushort_t* __restrict__ Vp,
              ushort_t* __restrict__ P, int S, int SC)
{
  __shared__ ushort_t As[4096];
  __shared__ ushort_t Bs[4096];
  const int tid = threadIdx.x;
  const int z = blockIdx.x;
  const int ch = blockIdx.y;
  const int lane = tid & 63, w = tid >> 6;
  const int wr = (w >> 1) * 64, wc = (w & 1) * 64;
  const int frow = lane & 15, q = lane >> 4;
  const long zoff = (long)z * S * 128 + ((long)(ch * SC) >> 3) * 1024;
  const ushort_t* Vg = Vp + zoff + lane * 8;
  const ushort_t* Kg = Kp + zoff + lane * 8;

  f32x4 acc[4][4];
  #pragma unroll
  for (int i = 0; i < 4; ++i)
    #pragma unroll
    for (int j = 0; j < 4; ++j) acc[i][j] = f32x4{0.f, 0.f, 0.f, 0.f};

  for (int s0 = 0; s0 < SC; s0 += 32) {
    const long go = ((long)s0 >> 3) * 1024;
    __syncthreads();
    gl16(Vg + go + (2 * w) * 512,     &As[(2 * w) * 512]);
    gl16(Vg + go + (2 * w + 1) * 512, &As[(2 * w + 1) * 512]);
    gl16(Kg + go + (2 * w) * 512,     &Bs[(2 * w) * 512]);
    gl16(Kg + go + (2 * w + 1) * 512, &Bs[(2 * w + 1) * 512]);
    __syncthreads();
    bfrag af[4], bf[4];
    #pragma unroll
    for (int i = 0; i < 4; ++i)
      af[i] = ldfrag(&As[q * 1024 + (wr + i * 16 + frow) * 8]);
    #pragma unroll
    for (int j = 0; j < 4; ++j)
      bf[j] = ldfrag(&Bs[q * 1024 + (wc + j * 16 + frow) * 8]);
    #pragma unroll
    for (int i = 0; i < 4; ++i)
      #pragma unroll
      for (int j = 0; j < 4; ++j)
        acc[i][j] = __builtin_amdgcn_mfma_f32_16x16x32_bf16(af[i], bf[j], acc[i][j], 0, 0, 0);
  }
  ushort_t* Pz = P + ((long)ch * 128 + z) * 16384;
  const int rb = q * 4;
  #pragma unroll
  for (int i = 0; i < 4; ++i)
    #pragma unroll
    for (int j = 0; j < 4; ++j)
      #pragma unroll
      for (int e = 0; e < 4; ++e)
        Pz[(long)(wr + i * 16 + rb + e) * 128 + (wc + j * 16 + frow)] =
            f2bf(acc[i][j][e]);
}

// sum bf16 partials over chunks -> bf16 AT.
__global__ __launch_bounds__(256)
void ktv_reduce(const ushort_t* __restrict__ P, ushort_t* __restrict__ AT, int nch)
{
  const long i = ((long)blockIdx.x * 256 + threadIdx.x) * 8;
  float s[8] = {0.f, 0.f, 0.f, 0.f, 0.f, 0.f, 0.f, 0.f};
  for (int c = 0; c < nch; ++c) {
    const us8 v = *(const us8*)(P + (long)c * 2097152 + i);
    #pragma unroll
    for (int k = 0; k < 8; ++k) s[k] += bf2f(v[k]);
  }
  us8 o;
  #pragma unroll
  for (int k = 0; k < 8; ++k) o[k] = f2bf(s[k]);
  *(us8*)(AT + i) = o;
}

// ---------------------------------------------------------------------------
// LayerNorm (final stage only), f32 in -> f32 out.
// ---------------------------------------------------------------------------
__global__ __launch_bounds__(256)
void layernorm_k(const float* __restrict__ X, const float* __restrict__ G,
                 const float* __restrict__ Bta, float* __restrict__ Y)
{
  const int row = blockIdx.x;
  const int t = threadIdx.x;
  const float4 v = *(const float4*)(X + (long)row * DIM + t * 4);
  float s  = v.x + v.y + v.z + v.w;
  float sq = v.x * v.x + v.y * v.y + v.z * v.z + v.w * v.w;
  #pragma unroll
  for (int o = 32; o; o >>= 1) { s += __shfl_xor(s, o); sq += __shfl_xor(sq, o); }
  __shared__ float ps[4], pq[4];
  if ((t & 63) == 0) { ps[t >> 6] = s; pq[t >> 6] = sq; }
  __syncthreads();
  s  = ps[0] + ps[1] + ps[2] + ps[3];
  sq = pq[0] + pq[1] + pq[2] + pq[3];
  const float mean = s * (1.0f / DIM);
  const float var  = sq * (1.0f / DIM) - mean * mean;
  const float rstd = rsqrtf(var + LN_EPS);
  const float4 gv = *(const float4*)(G + t * 4);
  const float4 bv = *(const float4*)(Bta + t * 4);
  float4 o;
  o.x = (v.x - mean) * rstd * gv.x + bv.x;
  o.y = (v.y - mean) * rstd * gv.y + bv.y;
  o.z = (v.z - mean) * rstd * gv.z + bv.z;
  o.w = (v.w - mean) * rstd * gv.w + bv.w;
  *(float4*)(Y + (long)row * DIM + t * 4) = o;
}

// ---------------------------------------------------------------------------
// Merged weight transpose: 6 tasks x 8 heads; task 5 (Wq2) scaled by g1[k].
// ---------------------------------------------------------------------------
struct TPack {
  const float* src[6];
  ushort_t* dst[6];
};

__global__ __launch_bounds__(256)
void transpose_all(TPack p, const float* __restrict__ g1)
{
  __shared__ float tile[32][33];
  const int task = blockIdx.z >> 3;
  const int z = blockIdx.z & 7;
  const int kb = blockIdx.y * 32;
  const int nb = blockIdx.x * 32;
  const float* src = p.src[task] + (long)z * DIM * DQh;
  ushort_t* dst = p.dst[task] + (long)z * DIM * DQh;
  const int tx = threadIdx.x & 31;
  const int ty = threadIdx.x >> 5;
  #pragma unroll
  for (int r = 0; r < 32; r += 8)
    tile[ty + r][tx] = src[(long)(kb + ty + r) * DQh + nb + tx];
  __syncthreads();
  const float gs = (task == 5) ? g1[kb + tx] : 1.0f;
  #pragma unroll
  for (int r = 0; r < 32; r += 8)
    dst[(long)(nb + ty + r) * DIM + kb + tx] = f2bf(tile[tx][ty + r] * gs);
}

// ---------------------------------------------------------------------------
// Merged elementwise casts: 8 tasks; task 4 (E1) scaled by g2[k].
// ---------------------------------------------------------------------------
struct CPack {
  const float* src[8];
  ushort_t* dst[8];
  const float* g2;
};

__global__ __launch_bounds__(256)
void cast_all(CPack p)
{
  const int bid = blockIdx.x;
  int t;
  long base;
  if      (bid < 16384) { t = 0; base = 0; }
  else if (bid < 49152) { t = 1; base = 16384; }
  else if (bid < 50176) { t = 2; base = 49152; }
  else if (bid < 51200) { t = 3; base = 50176; }
  else if (bid < 51712) { t = 4; base = 51200; }
  else if (bid < 52224) { t = 5; base = 51712; }
  else if (bid < 52736) { t = 6; base = 52224; }
  else                  { t = 7; base = 52736; }
  const long i = ((long)(bid - base) * 256 + threadIdx.x) * 4;
  const float4 v = *(const float4*)(p.src[t] + i);
  float4 o = v;
  if (t == 4) {
    const float4 gv = *(const float4*)(p.g2 + (i & 1023));
    o.x *= gv.x; o.y *= gv.y; o.z *= gv.z; o.w *= gv.w;
  }
  ushort4 sv = make_ushort4(f2bf(o.x), f2bf(o.y), f2bf(o.z), f2bf(o.w));
  *(ushort4*)(p.dst[t] + i) = sv;
}

// ---------------------------------------------------------------------------

extern "C" void kernel_launch(void* const* d_in, const int* in_sizes, int n_in,
                              void* d_out, int out_size, void* d_ws, size_t ws_size,
                              hipStream_t stream)
{
  (void)in_sizes; (void)n_in; (void)out_size; (void)ws_size;
  const float* mem = (const float*)d_in[0];
  const float* y0  = (const float*)d_in[1];
  const float* Wq1 = (const float*)d_in[2];
  const float* Wk1 = (const float*)d_in[3];
  const float* Wv1 = (const float*)d_in[4];
  const float* Wo1 = (const float*)d_in[5];
  const float* Wq2 = (const float*)d_in[6];
  const float* Wk2 = (const float*)d_in[7];
  const float* Wv2 = (const float*)d_in[8];
  const float* Wo2 = (const float*)d_in[9];
  const float* E1  = (const float*)d_in[10];
  const float* D1  = (const float*)d_in[11];
  const float* E2  = (const float*)d_in[12];
  const float* D2  = (const float*)d_in[13];
  const float* g1  = (const float*)d_in[14];
  const float* b1  = (const float*)d_in[15];
  const float* g2  = (const float*)d_in[16];
  const float* b2  = (const float*)d_in[17];
  const float* g3  = (const float*)d_in[18];
  const float* b3  = (const float*)d_in[19];

  char* ws = (char*)d_ws;
  const size_t MB = 1ull << 20;
  ushort_t* wkv1  = (ushort_t*)(ws + 0 * MB);
  ushort_t* wq1t  = (ushort_t*)(ws + 4 * MB);
  ushort_t* wkv2  = (ushort_t*)(ws + 6 * MB);
  ushort_t* wq2t  = (ushort_t*)(ws + 10 * MB);   // g1-scaled
  ushort_t* wo1b  = (ushort_t*)(ws + 12 * MB);
  ushort_t* wo2b  = (ushort_t*)(ws + 14 * MB);
  ushort_t* e1b   = (ushort_t*)(ws + 16 * MB);   // g2-scaled
  ushort_t* d1b   = (ushort_t*)(ws + 17 * MB);
  ushort_t* e2b   = (ushort_t*)(ws + 18 * MB);
  ushort_t* d2b   = (ushort_t*)(ws + 19 * MB);
  ushort_t* y0b   = (ushort_t*)(ws + 20 * MB);   // 32 MB
  ushort_t* memb  = (ushort_t*)(ws + 52 * MB);   // 64 MB
  ushort_t* bn2   = (ushort_t*)(ws + 116 * MB);  // 16 MB
  float*    pstat1 = (float*)(ws + 132 * MB);    // 2 MB
  float*    pstat2 = (float*)(ws + 134 * MB);    // 2 MB
  float*    stats1 = (float*)(ws + 136 * MB);    // 128 KB
  float*    stats2 = (float*)(ws + 137 * MB);    // 128 KB
  float*    c1q    = (float*)(ws + 138 * MB);
  float*    c2q    = (float*)(ws + 139 * MB);
  float*    c1e    = (float*)(ws + 140 * MB);
  float*    c2e    = (float*)(ws + 141 * MB);
  ushort_t* kbuf  = (ushort_t*)(ws + 148 * MB);  // 64 MB (s-blocked)
  ushort_t* vbuf  = (ushort_t*)(ws + 212 * MB);  // 64 MB (s-blocked)
  ushort_t* amatT = (ushort_t*)(ws + 276 * MB);  // 4 MB
  ushort_t* attnb = (ushort_t*)(ws + 280 * MB);  // 32 MB
  float*    ybuf  = (float*)(ws + 312 * MB);     // 64 MB (f32 y-chain)
  ushort_t* ybf   = (ushort_t*)(ws + 376 * MB);  // 32 MB (bf16 y)
  ushort_t* hbuf  = (ushort_t*)(ws + 408 * MB);  // 32 MB
  ushort_t* pbuf  = (ushort_t*)(ws + 440 * MB);  // 16 MB (bf16 ktv partials)
  ushort_t* bn1   = attnb;                       // reuse

  // ---- prep (3 dispatches) ----
  CPack cp;
  cp.src[0] = y0;  cp.dst[0] = y0b;
  cp.src[1] = mem; cp.dst[1] = memb;
  cp.src[2] = Wo1; cp.dst[2] = wo1b;
  cp.src[3] = Wo2; cp.dst[3] = wo2b;
  cp.src[4] = E1;  cp.dst[4] = e1b;
  cp.src[5] = D1;  cp.dst[5] = d1b;
  cp.src[6] = E2;  cp.dst[6] = e2b;
  cp.src[7] = D2;  cp.dst[7] = d2b;
  cp.g2 = g2;
  cast_all<<<53248, 256, 0, stream>>>(cp);

  TPack tp;
  tp.src[0] = Wk1; tp.dst[0] = wkv1;
  tp.src[1] = Wv1; tp.dst[1] = wkv1 + (1 << 20);
  tp.src[2] = Wq1; tp.dst[2] = wq1t;
  tp.src[3] = Wk2; tp.dst[3] = wkv2;
  tp.src[4] = Wv2; tp.dst[4] = wkv2 + (1 << 20);
  tp.src[5] = Wq2; tp.dst[5] = wq2t;
  transpose_all<<<dim3(4, 32, 48), 256, 0, stream>>>(tp, g1);

  cvec2<<<384, 256, 0, stream>>>(Wq2, g1, b1, c1q, c2q, E1, g2, b2, c1e, c2e);

  // ---- phase 1: masked self linear-attention ----
  gemm_qkv<<<dim3(16, 128), 256, 0, stream>>>(
      y0b, wkv1, kbuf, vbuf, NB * ST, 2048, DIM, 10, 0b01);
  gemm_ktv<<<dim3(128, 4), 256, 0, stream>>>(kbuf, vbuf, pbuf, ST, 256);
  ktv_reduce<<<1024, 256, 0, stream>>>(pbuf, amatT, 4);
  fused_qa<true, false><<<dim3(8, 128), 256, 0, stream>>>(
      y0b, wq1t, amatT, attnb, nullptr, nullptr, nullptr);
  gemm_bb<ST_YSTAT><<<dim3(8, 128), 256, 0, stream>>>(
      attnb, wo1b, y0, nullptr, nullptr, nullptr, nullptr, nullptr,
      ybf, ybuf, pstat1, NB * ST, DIM, DIM);
  stats_reduce<<<64, 256, 0, stream>>>(pstat1, stats1);

  // ---- phase 2: cross linear-attention ----
  gemm_qkv<<<dim3(16, 256), 256, 0, stream>>>(
      memb, wkv2, kbuf, vbuf, NB * SM, 2048, DIM, 11, 0b01);
  gemm_ktv<<<dim3(128, 4), 256, 0, stream>>>(kbuf, vbuf, pbuf, SM, 512);
  ktv_reduce<<<1024, 256, 0, stream>>>(pbuf, amatT, 4);
  fused_qa<false, true><<<dim3(8, 128), 256, 0, stream>>>(
      ybf, wq2t, amatT, attnb, stats1, c1q, c2q);
  gemm_bb<ST_ZSTAT><<<dim3(8, 128), 256, 0, stream>>>(
      attnb, wo2b, ybuf, stats1, g1, b1, nullptr, nullptr,
      ybf, ybuf, pstat2, NB * ST, DIM, DIM);
  stats_reduce<<<64, 256, 0, stream>>>(pstat2, stats2);

  // ---- phase 3: LFFN ----
  gemm_bb<ST_ABS><<<dim3(4, 128), 256, 0, stream>>>(
      ybf, e1b, nullptr, stats2, nullptr, nullptr, c1e, c2e,
      bn1, nullptr, nullptr, NB * ST, 512, DIM);
  gemm_bb<ST_SWISH><<<dim3(8, 128), 256, 0, stream>>>(
      bn1, d1b, nullptr, nullptr, nullptr, nullptr, nullptr, nullptr,
      hbuf, nullptr, nullptr, NB * ST, DIM, 512);
  gemm_bb<ST_BF16><<<dim3(4, 128), 256, 0, stream>>>(
      hbuf, e2b, nullptr, nullptr, nullptr, nullptr, nullptr, nullptr,
      bn2, nullptr, nullptr, NB * ST, 512, DIM);
  gemm_bb<ST_ZRES><<<dim3(8, 128), 256, 0, stream>>>(
      bn2, d2b, ybuf, stats2, g2, b2, nullptr, nullptr,
      nullptr, ybuf, nullptr, NB * ST, DIM, 512);
  layernorm_k<<<NB * ST, 256, 0, stream>>>(ybuf, g3, b3, (float*)d_out);
}

// Round 15
// 813.544 us; speedup vs baseline: 3.2593x; 1.9257x over previous
//
#include <hip/hip_runtime.h>
#include <hip/hip_bf16.h>

#define DEVI __device__ __forceinline__

typedef __bf16 bfrag __attribute__((ext_vector_type(8)));
typedef unsigned short us8 __attribute__((ext_vector_type(8)));
typedef float f32x4 __attribute__((ext_vector_type(4)));
typedef unsigned short ushort_t;

static constexpr int NB  = 16;
static constexpr int NH  = 8;
static constexpr int DIM = 1024;
static constexpr int DQh = 128;
static constexpr int ST  = 1024;
static constexpr int SM  = 2048;
static constexpr float INV_SCALE = 0.29730177875068026f; // 1 / 128^0.25
static constexpr float LN_EPS = 1e-5f;

DEVI ushort_t f2bf(float f) {
  __hip_bfloat16 h = __float2bfloat16(f);
  return __builtin_bit_cast(ushort_t, h);
}
DEVI float bf2f(ushort_t u) {
  return __bfloat162float(__builtin_bit_cast(__hip_bfloat16, u));
}
DEVI bfrag ldfrag(const ushort_t* p) {
  return __builtin_bit_cast(bfrag, *(const us8*)p);
}
DEVI void gl16(const ushort_t* g, ushort_t* l) {
  __builtin_amdgcn_global_load_lds(
      (const __attribute__((address_space(1))) void*)g,
      (__attribute__((address_space(3))) void*)l, 16, 0, 0);
}

enum { ST_BF16 = 0, ST_SWISH = 1, ST_ABS = 2, ST_YSTAT = 3, ST_ZSTAT = 4,
       ST_ZRES = 5 };

// ---------------------------------------------------------------------------
// K/V projection GEMM with fused wave-local softmax; s-blocked store
// [z][S/8][128 d][8 s] consumed by gemm_ktv. Pure gl16 staging.
// launch_bounds(256,4): ~48 VGPR + 64 acc regs (unified file) ≈ 112/wave ->
// 4 waves/SIMD is the HW max; bounds 6/8 forced spill (R13/R14 disasters).
// ---------------------------------------------------------------------------
__global__ __launch_bounds__(256, 4)
void gemm_qkv(const ushort_t* __restrict__ A, const ushort_t* __restrict__ Bt,
              ushort_t* __restrict__ P0, ushort_t* __restrict__ P1,
              int M, int N, int K, int logS, int smflags)
{
  __shared__ ushort_t As[128][32];
  __shared__ ushort_t Bs[128][32];
  const int tid = threadIdx.x;
  int bx = blockIdx.x, by = blockIdx.y;
  {
    const int gx = gridDim.x;
    const int nwg = gx * gridDim.y;
    int bid = by * gx + bx;
    if ((nwg & 7) == 0) bid = (bid & 7) * (nwg >> 3) + (bid >> 3);  // XCD swizzle
    bx = bid % gx; by = bid / gx;
  }
  const int m0 = by * 128, n0 = bx * 128;

  const int lane = tid & 63;
  const int w = tid >> 6;
  const int wr = w * 32;
  const int frow = lane & 15;
  const int q = lane >> 4;

  const int grow = lane >> 2;
  const int gk = ((lane & 3) ^ ((lane >> 3) & 3)) * 8;
  const ushort_t* Ag = A + (long)(m0 + w * 32 + grow) * K + gk;
  const ushort_t* Bg = Bt + (long)(n0 + w * 32 + grow) * K + gk;

  f32x4 acc[2][8];
  #pragma unroll
  for (int i = 0; i < 2; ++i)
    #pragma unroll
    for (int j = 0; j < 8; ++j) acc[i][j] = f32x4{0.f, 0.f, 0.f, 0.f};

  const int kqs = (frow >> 1) & 3;
  for (int k0 = 0; k0 < K; k0 += 32) {
    __syncthreads();
    gl16(Ag + k0,                &As[w * 32][0]);
    gl16(Ag + k0 + (long)16 * K, &As[w * 32 + 16][0]);
    gl16(Bg + k0,                &Bs[w * 32][0]);
    gl16(Bg + k0 + (long)16 * K, &Bs[w * 32 + 16][0]);
    __syncthreads();
    const int kq = (q ^ kqs) * 8;
    const bfrag af0 = ldfrag(&As[wr + frow][kq]);
    const bfrag af1 = ldfrag(&As[wr + 16 + frow][kq]);
    #pragma unroll
    for (int j = 0; j < 8; ++j) {
      const bfrag bf = ldfrag(&Bs[j * 16 + frow][kq]);
      acc[0][j] = __builtin_amdgcn_mfma_f32_16x16x32_bf16(af0, bf, acc[0][j], 0, 0, 0);
      acc[1][j] = __builtin_amdgcn_mfma_f32_16x16x32_bf16(af1, bf, acc[1][j], 0, 0, 0);
    }
  }

  const int sel = n0 >> 10;
  const bool dosm = (smflags >> sel) & 1;
  const int h = (n0 >> 7) & 7;
  ushort_t* __restrict__ Bq = (sel == 0) ? P0 : P1;
  const int S = 1 << logS;
  const int b_blk = m0 >> logS;
  const int s_m0 = m0 & (S - 1);

  if (dosm) {
    #pragma unroll
    for (int i = 0; i < 2; ++i) {
      #pragma unroll
      for (int e = 0; e < 4; ++e) {
        float v[8];
        #pragma unroll
        for (int j = 0; j < 8; ++j) v[j] = acc[i][j][e] * INV_SCALE;
        float mx = v[0];
        #pragma unroll
        for (int j = 1; j < 8; ++j) mx = fmaxf(mx, v[j]);
        mx = fmaxf(mx, __shfl_xor(mx, 1));
        mx = fmaxf(mx, __shfl_xor(mx, 2));
        mx = fmaxf(mx, __shfl_xor(mx, 4));
        mx = fmaxf(mx, __shfl_xor(mx, 8));
        float sm = 0.f;
        #pragma unroll
        for (int j = 0; j < 8; ++j) { v[j] = __expf(v[j] - mx); sm += v[j]; }
        sm += __shfl_xor(sm, 1);
        sm += __shfl_xor(sm, 2);
        sm += __shfl_xor(sm, 4);
        sm += __shfl_xor(sm, 8);
        const float inv = 1.0f / sm;
        #pragma unroll
        for (int j = 0; j < 8; ++j) acc[i][j][e] = v[j] * inv;
      }
    }
  }

  ushort_t* zbase = Bq + (long)(h * 16 + b_blk) * S * 128;
  #pragma unroll
  for (int i = 0; i < 2; ++i) {
    const int sb = s_m0 + wr + i * 16 + q * 4;
    ushort_t* rowb = zbase + (long)(sb >> 3) * 1024 + (sb & 7);
    #pragma unroll
    for (int j = 0; j < 8; ++j) {
      ushort4 o = make_ushort4(f2bf(acc[i][j][0]), f2bf(acc[i][j][1]),
                               f2bf(acc[i][j][2]), f2bf(acc[i][j][3]));
      *(ushort4*)(rowb + (j * 16 + frow) * 8) = o;
    }
  }
}

// ---------------------------------------------------------------------------
// Fused Q path: scores -> (optional LN-absorb) -> wave-local softmax -> P@A
// -> scramble store.
// ---------------------------------------------------------------------------
template<bool MASKED, bool ABSORB>
__global__ __launch_bounds__(256, 3)
void fused_qa(const ushort_t* __restrict__ A, const ushort_t* __restrict__ Wq,
              const ushort_t* __restrict__ AT, ushort_t* __restrict__ Out,
              const float* __restrict__ SIn, const float* __restrict__ C1,
              const float* __restrict__ C2)
{
  __shared__ ushort_t As[128][32];
  __shared__ ushort_t Bs[128][32];
  __shared__ ushort_t Ps[4][32][128];
  const int tid = threadIdx.x;
  int h = blockIdx.x, by = blockIdx.y;
  {
    const int gx = gridDim.x;
    const int nwg = gx * gridDim.y;
    int bid = by * gx + h;
    if ((nwg & 7) == 0) bid = (bid & 7) * (nwg >> 3) + (bid >> 3);
    h = bid % gx; by = bid / gx;
  }
  const int m0 = by * 128;

  const int lane = tid & 63;
  const int w = tid >> 6;
  const int wr = w * 32;
  const int frow = lane & 15;
  const int q = lane >> 4;

  const int grow = lane >> 2;
  const int gk = ((lane & 3) ^ ((lane >> 3) & 3)) * 8;
  const ushort_t* Ag = A + (long)(m0 + w * 32 + grow) * 1024 + gk;
  const ushort_t* Bg = Wq + (long)(h * 128 + w * 32 + grow) * 1024 + gk;

  f32x4 acc[2][8];
  #pragma unroll
  for (int i = 0; i < 2; ++i)
    #pragma unroll
    for (int j = 0; j < 8; ++j) acc[i][j] = f32x4{0.f, 0.f, 0.f, 0.f};

  const int kqs = (frow >> 1) & 3;
  for (int k0 = 0; k0 < 1024; k0 += 32) {
    __syncthreads();
    gl16(Ag + k0,             &As[w * 32][0]);
    gl16(Ag + k0 + 16 * 1024, &As[w * 32 + 16][0]);
    gl16(Bg + k0,             &Bs[w * 32][0]);
    gl16(Bg + k0 + 16 * 1024, &Bs[w * 32 + 16][0]);
    __syncthreads();
    const int kq = (q ^ kqs) * 8;
    const bfrag af0 = ldfrag(&As[wr + frow][kq]);
    const bfrag af1 = ldfrag(&As[wr + 16 + frow][kq]);
    #pragma unroll
    for (int j = 0; j < 8; ++j) {
      const bfrag bf = ldfrag(&Bs[j * 16 + frow][kq]);
      acc[0][j] = __builtin_amdgcn_mfma_f32_16x16x32_bf16(af0, bf, acc[0][j], 0, 0, 0);
      acc[1][j] = __builtin_amdgcn_mfma_f32_16x16x32_bf16(af1, bf, acc[1][j], 0, 0, 0);
    }
  }

  float c1j[8], c2j[8];
  if (ABSORB) {
    #pragma unroll
    for (int j = 0; j < 8; ++j) {
      c1j[j] = C1[h * 128 + j * 16 + frow];
      c2j[j] = C2[h * 128 + j * 16 + frow];
    }
  }

  #pragma unroll
  for (int i = 0; i < 2; ++i) {
    #pragma unroll
    for (int e = 0; e < 4; ++e) {
      const int row32 = i * 16 + q * 4 + e;
      const int gmr = m0 + wr + row32;
      const int srow = gmr & (ST - 1);
      float v[8];
      #pragma unroll
      for (int j = 0; j < 8; ++j) v[j] = acc[i][j][e];
      if (ABSORB) {
        const float mu = SIn[gmr * 2], rr = SIn[gmr * 2 + 1];
        #pragma unroll
        for (int j = 0; j < 8; ++j)
          v[j] = rr * v[j] - rr * mu * c1j[j] + c2j[j];
      }
      #pragma unroll
      for (int j = 0; j < 8; ++j) {
        v[j] *= INV_SCALE;
        if (MASKED && (j * 16 + frow) > srow) v[j] = -3.0e38f;
      }
      float mx = v[0];
      #pragma unroll
      for (int j = 1; j < 8; ++j) mx = fmaxf(mx, v[j]);
      mx = fmaxf(mx, __shfl_xor(mx, 1));
      mx = fmaxf(mx, __shfl_xor(mx, 2));
      mx = fmaxf(mx, __shfl_xor(mx, 4));
      mx = fmaxf(mx, __shfl_xor(mx, 8));
      float sm = 0.f;
      #pragma unroll
      for (int j = 0; j < 8; ++j) { v[j] = __expf(v[j] - mx); sm += v[j]; }
      sm += __shfl_xor(sm, 1);
      sm += __shfl_xor(sm, 2);
      sm += __shfl_xor(sm, 4);
      sm += __shfl_xor(sm, 8);
      const float inv = 1.0f / sm;
      const int sw = (row32 >> 1) & 3;
      ushort_t* pr = &Ps[w][row32][0];
      #pragma unroll
      for (int j = 0; j < 8; ++j) {
        const int c = j * 16 + frow;
        const int pos = (c & ~31) | ((((c >> 3) & 3) ^ sw) << 3) | (c & 7);
        pr[pos] = f2bf(v[j] * inv);
      }
    }
  }

  f32x4 acc2[2][8];
  #pragma unroll
  for (int i = 0; i < 2; ++i)
    #pragma unroll
    for (int j = 0; j < 8; ++j) acc2[i][j] = f32x4{0.f, 0.f, 0.f, 0.f};

  const ushort_t* Atg = AT + (long)((h << 4) + (m0 >> 10)) * 16384 +
                        (long)(w * 32 + grow) * 128 + gk;
  for (int d0 = 0; d0 < 128; d0 += 32) {
    __syncthreads();
    gl16(Atg + d0,            &Bs[w * 32][0]);
    gl16(Atg + d0 + 16 * 128, &Bs[w * 32 + 16][0]);
    __syncthreads();
    const int kq = (q ^ kqs) * 8;
    const bfrag af0 = ldfrag(&Ps[w][frow][d0 + kq]);
    const bfrag af1 = ldfrag(&Ps[w][16 + frow][d0 + kq]);
    #pragma unroll
    for (int j = 0; j < 8; ++j) {
      const bfrag bf = ldfrag(&Bs[j * 16 + frow][kq]);
      acc2[0][j] = __builtin_amdgcn_mfma_f32_16x16x32_bf16(af0, bf, acc2[0][j], 0, 0, 0);
      acc2[1][j] = __builtin_amdgcn_mfma_f32_16x16x32_bf16(af1, bf, acc2[1][j], 0, 0, 0);
    }
  }

  ushort_t* ob = Out + (long)(m0 >> 10) * (ST * DIM);
  #pragma unroll
  for (int i = 0; i < 2; ++i) {
    #pragma unroll
    for (int e = 0; e < 4; ++e) {
      const int srow = (m0 + wr + i * 16 + q * 4 + e) & (ST - 1);
      ushort_t* orow = ob + (long)(h * 128 + (srow >> 3)) * DIM + (srow & 7) * 128;
      #pragma unroll
      for (int j = 0; j < 8; ++j)
        orow[j * 16 + frow] = f2bf(acc2[i][j][e]);
    }
  }
}

// ---------------------------------------------------------------------------
// 128x128-tile bf16 GEMM (m97 structure), 2x2 waves. Epilogues as R9.
// ---------------------------------------------------------------------------
template<int STORE>
__global__ __launch_bounds__(256, 2)
void gemm_bb(const ushort_t* __restrict__ A, const ushort_t* __restrict__ Bt,
             const float* __restrict__ Res, const float* __restrict__ SIn,
             const float* __restrict__ Gv, const float* __restrict__ Bv,
             const float* __restrict__ C1, const float* __restrict__ C2,
             ushort_t* __restrict__ Pb, float* __restrict__ Cf,
             float* __restrict__ PStat, int M, int N, int K)
{
  __shared__ ushort_t As[128][32];
  __shared__ ushort_t Bs[128][32];
  const int tid = threadIdx.x;
  int bx = blockIdx.x, by = blockIdx.y;
  {
    const int gx = gridDim.x;
    const int nwg = gx * gridDim.y;
    int bid = by * gx + bx;
    if ((nwg & 7) == 0) bid = (bid & 7) * (nwg >> 3) + (bid >> 3);
    bx = bid % gx; by = bid / gx;
  }
  const int m0 = by * 128, n0 = bx * 128;

  const int lane = tid & 63;
  const int w = tid >> 6;
  const int wr = (w >> 1) * 64, wc = (w & 1) * 64;
  const int frow = lane & 15;
  const int q = lane >> 4;

  const int grow = lane >> 2;
  const int gk = ((lane & 3) ^ ((lane >> 3) & 3)) * 8;
  const ushort_t* Ag = A + (long)(m0 + w * 32 + grow) * K + gk;
  const ushort_t* Bg = Bt + (long)(n0 + w * 32 + grow) * K + gk;

  f32x4 acc[4][4];
  #pragma unroll
  for (int i = 0; i < 4; ++i)
    #pragma unroll
    for (int j = 0; j < 4; ++j) acc[i][j] = f32x4{0.f, 0.f, 0.f, 0.f};

  const int kqs = (frow >> 1) & 3;
  for (int k0 = 0; k0 < K; k0 += 32) {
    __syncthreads();
    gl16(Ag + k0,                &As[w * 32][0]);
    gl16(Ag + k0 + (long)16 * K, &As[w * 32 + 16][0]);
    gl16(Bg + k0,                &Bs[w * 32][0]);
    gl16(Bg + k0 + (long)16 * K, &Bs[w * 32 + 16][0]);
    __syncthreads();
    const int kq = (q ^ kqs) * 8;
    bfrag af[4], bf[4];
    #pragma unroll
    for (int i = 0; i < 4; ++i) af[i] = ldfrag(&As[wr + i * 16 + frow][kq]);
    #pragma unroll
    for (int j = 0; j < 4; ++j) bf[j] = ldfrag(&Bs[wc + j * 16 + frow][kq]);
    #pragma unroll
    for (int i = 0; i < 4; ++i)
      #pragma unroll
      for (int j = 0; j < 4; ++j)
        acc[i][j] = __builtin_amdgcn_mfma_f32_16x16x32_bf16(af[i], bf[j], acc[i][j], 0, 0, 0);
  }

  const int rb = q * 4;
  if constexpr (STORE == ST_YSTAT || STORE == ST_ZSTAT) {
    float gvj[4], bvj[4];
    if constexpr (STORE == ST_ZSTAT) {
      #pragma unroll
      for (int j = 0; j < 4; ++j) {
        gvj[j] = Gv[n0 + wc + j * 16 + frow];
        bvj[j] = Bv[n0 + wc + j * 16 + frow];
      }
    }
    #pragma unroll
    for (int i = 0; i < 4; ++i) {
      #pragma unroll
      for (int e = 0; e < 4; ++e) {
        const int gm = m0 + wr + i * 16 + rb + e;
        float mu = 0.f, rr = 0.f;
        if constexpr (STORE == ST_ZSTAT) { mu = SIn[gm * 2]; rr = SIn[gm * 2 + 1]; }
        float s = 0.f, sq = 0.f, vals[4];
        #pragma unroll
        for (int j = 0; j < 4; ++j) {
          const int gn = n0 + wc + j * 16 + frow;
          float rv = Res[(long)gm * N + gn];
          if constexpr (STORE == ST_ZSTAT) rv = (rv - mu) * rr * gvj[j] + bvj[j];
          const float v = acc[i][j][e] + rv;
          vals[j] = v; s += v; sq += v * v;
        }
        #pragma unroll
        for (int j = 0; j < 4; ++j) {
          const int gn = n0 + wc + j * 16 + frow;
          Cf[(long)gm * N + gn] = vals[j];
          Pb[(long)gm * N + gn] = f2bf(vals[j]);
        }
        s += __shfl_xor(s, 1);  sq += __shfl_xor(sq, 1);
        s += __shfl_xor(s, 2);  sq += __shfl_xor(sq, 2);
        s += __shfl_xor(s, 4);  sq += __shfl_xor(sq, 4);
        s += __shfl_xor(s, 8);  sq += __shfl_xor(sq, 8);
        if (frow == 0) {
          const int p = (n0 >> 7) * 2 + (wc >> 6);
          PStat[((long)gm * 16 + p) * 2]     = s;
          PStat[((long)gm * 16 + p) * 2 + 1] = sq;
        }
      }
    }
  } else if constexpr (STORE == ST_ABS) {
    float c1j[4], c2j[4];
    #pragma unroll
    for (int j = 0; j < 4; ++j) {
      c1j[j] = C1[n0 + wc + j * 16 + frow];
      c2j[j] = C2[n0 + wc + j * 16 + frow];
    }
    #pragma unroll
    for (int i = 0; i < 4; ++i) {
      #pragma unroll
      for (int e = 0; e < 4; ++e) {
        const int gm = m0 + wr + i * 16 + rb + e;
        const float mu = SIn[gm * 2], rr = SIn[gm * 2 + 1];
        #pragma unroll
        for (int j = 0; j < 4; ++j) {
          const int gn = n0 + wc + j * 16 + frow;
          const float v = rr * acc[i][j][e] - rr * mu * c1j[j] + c2j[j];
          Pb[(long)gm * N + gn] = f2bf(v);
        }
      }
    }
  } else if constexpr (STORE == ST_ZRES) {
    float gvj[4], bvj[4];
    #pragma unroll
    for (int j = 0; j < 4; ++j) {
      gvj[j] = Gv[n0 + wc + j * 16 + frow];
      bvj[j] = Bv[n0 + wc + j * 16 + frow];
    }
    #pragma unroll
    for (int i = 0; i < 4; ++i) {
      #pragma unroll
      for (int e = 0; e < 4; ++e) {
        const int gm = m0 + wr + i * 16 + rb + e;
        const float mu = SIn[gm * 2], rr = SIn[gm * 2 + 1];
        #pragma unroll
        for (int j = 0; j < 4; ++j) {
          const int gn = n0 + wc + j * 16 + frow;
          const float rv = Res[(long)gm * N + gn];
          const float z = (rv - mu) * rr * gvj[j] + bvj[j];
          Cf[(long)gm * N + gn] = acc[i][j][e] + z;
        }
      }
    }
  } else {
    #pragma unroll
    for (int i = 0; i < 4; ++i) {
      #pragma unroll
      for (int j = 0; j < 4; ++j) {
        #pragma unroll
        for (int e = 0; e < 4; ++e) {
          const int gm = m0 + wr + i * 16 + rb + e;
          const int gn = n0 + wc + j * 16 + frow;
          float val = acc[i][j][e];
          if constexpr (STORE == ST_SWISH) val = val / (1.0f + __expf(-val));
          Pb[(long)gm * N + gn] = f2bf(val);
        }
      }
    }
  }
}

// partial stats [M][16][2] -> per-row (mu, rstd)
__global__ __launch_bounds__(256)
void stats_reduce(const float* __restrict__ PS, float* __restrict__ SO)
{
  const int row = blockIdx.x * 256 + threadIdx.x;
  float s = 0.f, sq = 0.f;
  const float* p = PS + (long)row * 32;
  #pragma unroll
  for (int k = 0; k < 16; ++k) { s += p[2 * k]; sq += p[2 * k + 1]; }
  const float mu = s * (1.0f / 1024.0f);
  const float var = sq * (1.0f / 1024.0f) - mu * mu;
  SO[row * 2] = mu;
  SO[row * 2 + 1] = rsqrtf(var + LN_EPS);
}

// ---------------------------------------------------------------------------
// Merged c-vector kernel.
// ---------------------------------------------------------------------------
DEVI void cvec_body(const float* W, const float* g, const float* b,
                    float* c1, float* c2, int n, int lane,
                    long hstride, int nb_h, int nstride, int kstride, int K)
{
  const long base = (long)(n / nb_h) * hstride + (long)(n % nb_h) * nstride;
  float s1 = 0.f, s2 = 0.f;
  for (int k = lane; k < K; k += 64) {
    const float wv = W[base + (long)k * kstride];
    s1 += g[k] * wv; s2 += b[k] * wv;
  }
  #pragma unroll
  for (int o = 32; o; o >>= 1) { s1 += __shfl_xor(s1, o); s2 += __shfl_xor(s2, o); }
  if (lane == 0) { c1[n] = s1; c2[n] = s2; }
}

__global__ __launch_bounds__(256)
void cvec2(const float* __restrict__ Wq2, const float* __restrict__ g1,
           const float* __restrict__ b1, float* __restrict__ c1q,
           float* __restrict__ c2q,
           const float* __restrict__ E1, const float* __restrict__ g2,
           const float* __restrict__ b2, float* __restrict__ c1e,
           float* __restrict__ c2e)
{
  const int lane = threadIdx.x & 63;
  if (blockIdx.x < 256) {
    const int n = (blockIdx.x * 256 + threadIdx.x) >> 6;
    cvec_body(Wq2, g1, b1, c1q, c2q, n, lane, (long)DIM * DQh, 128, 1, 128, 1024);
  } else {
    const int n = ((blockIdx.x - 256) * 256 + threadIdx.x) >> 6;
    cvec_body(E1, g2, b2, c1e, c2e, n, lane, 0, 512, 1024, 1, 1024);
  }
}

// ---------------------------------------------------------------------------
// Split-S K^T·V from the s-blocked layout; bf16 partials.
// ---------------------------------------------------------------------------
__global__ __launch_bounds__(256, 2)
void gemm_ktv(const ushort_t* __restrict__ Kp, const ushort_t* __restrict__ Vp,
              ushort_t* __restrict__ P, int S, int SC)
{
  __shared__ ushort_t As[4096];
  __shared__ ushort_t Bs[4096];
  const int tid = threadIdx.x;
  const int z = blockIdx.x;
  const int ch = blockIdx.y;
  const int lane = tid & 63, w = tid >> 6;
  const int wr = (w >> 1) * 64, wc = (w & 1) * 64;
  const int frow = lane & 15, q = lane >> 4;
  const long zoff = (long)z * S * 128 + ((long)(ch * SC) >> 3) * 1024;
  const ushort_t* Vg = Vp + zoff + lane * 8;
  const ushort_t* Kg = Kp + zoff + lane * 8;

  f32x4 acc[4][4];
  #pragma unroll
  for (int i = 0; i < 4; ++i)
    #pragma unroll
    for (int j = 0; j < 4; ++j) acc[i][j] = f32x4{0.f, 0.f, 0.f, 0.f};

  for (int s0 = 0; s0 < SC; s0 += 32) {
    const long go = ((long)s0 >> 3) * 1024;
    __syncthreads();
    gl16(Vg + go + (2 * w) * 512,     &As[(2 * w) * 512]);
    gl16(Vg + go + (2 * w + 1) * 512, &As[(2 * w + 1) * 512]);
    gl16(Kg + go + (2 * w) * 512,     &Bs[(2 * w) * 512]);
    gl16(Kg + go + (2 * w + 1) * 512, &Bs[(2 * w + 1) * 512]);
    __syncthreads();
    bfrag af[4], bf[4];
    #pragma unroll
    for (int i = 0; i < 4; ++i)
      af[i] = ldfrag(&As[q * 1024 + (wr + i * 16 + frow) * 8]);
    #pragma unroll
    for (int j = 0; j < 4; ++j)
      bf[j] = ldfrag(&Bs[q * 1024 + (wc + j * 16 + frow) * 8]);
    #pragma unroll
    for (int i = 0; i < 4; ++i)
      #pragma unroll
      for (int j = 0; j < 4; ++j)
        acc[i][j] = __builtin_amdgcn_mfma_f32_16x16x32_bf16(af[i], bf[j], acc[i][j], 0, 0, 0);
  }
  ushort_t* Pz = P + ((long)ch * 128 + z) * 16384;
  const int rb = q * 4;
  #pragma unroll
  for (int i = 0; i < 4; ++i)
    #pragma unroll
    for (int j = 0; j < 4; ++j)
      #pragma unroll
      for (int e = 0; e < 4; ++e)
        Pz[(long)(wr + i * 16 + rb + e) * 128 + (wc + j * 16 + frow)] =
            f2bf(acc[i][j][e]);
}

// sum bf16 partials over chunks -> bf16 AT.
__global__ __launch_bounds__(256)
void ktv_reduce(const ushort_t* __restrict__ P, ushort_t* __restrict__ AT, int nch)
{
  const long i = ((long)blockIdx.x * 256 + threadIdx.x) * 8;
  float s[8] = {0.f, 0.f, 0.f, 0.f, 0.f, 0.f, 0.f, 0.f};
  for (int c = 0; c < nch; ++c) {
    const us8 v = *(const us8*)(P + (long)c * 2097152 + i);
    #pragma unroll
    for (int k = 0; k < 8; ++k) s[k] += bf2f(v[k]);
  }
  us8 o;
  #pragma unroll
  for (int k = 0; k < 8; ++k) o[k] = f2bf(s[k]);
  *(us8*)(AT + i) = o;
}

// ---------------------------------------------------------------------------
// LayerNorm (final stage only), f32 in -> f32 out.
// ---------------------------------------------------------------------------
__global__ __launch_bounds__(256)
void layernorm_k(const float* __restrict__ X, const float* __restrict__ G,
                 const float* __restrict__ Bta, float* __restrict__ Y)
{
  const int row = blockIdx.x;
  const int t = threadIdx.x;
  const float4 v = *(const float4*)(X + (long)row * DIM + t * 4);
  float s  = v.x + v.y + v.z + v.w;
  float sq = v.x * v.x + v.y * v.y + v.z * v.z + v.w * v.w;
  #pragma unroll
  for (int o = 32; o; o >>= 1) { s += __shfl_xor(s, o); sq += __shfl_xor(sq, o); }
  __shared__ float ps[4], pq[4];
  if ((t & 63) == 0) { ps[t >> 6] = s; pq[t >> 6] = sq; }
  __syncthreads();
  s  = ps[0] + ps[1] + ps[2] + ps[3];
  sq = pq[0] + pq[1] + pq[2] + pq[3];
  const float mean = s * (1.0f / DIM);
  const float var  = sq * (1.0f / DIM) - mean * mean;
  const float rstd = rsqrtf(var + LN_EPS);
  const float4 gv = *(const float4*)(G + t * 4);
  const float4 bv = *(const float4*)(Bta + t * 4);
  float4 o;
  o.x = (v.x - mean) * rstd * gv.x + bv.x;
  o.y = (v.y - mean) * rstd * gv.y + bv.y;
  o.z = (v.z - mean) * rstd * gv.z + bv.z;
  o.w = (v.w - mean) * rstd * gv.w + bv.w;
  *(float4*)(Y + (long)row * DIM + t * 4) = o;
}

// ---------------------------------------------------------------------------
// Merged weight transpose: 6 tasks x 8 heads; task 5 (Wq2) scaled by g1[k].
// ---------------------------------------------------------------------------
struct TPack {
  const float* src[6];
  ushort_t* dst[6];
};

__global__ __launch_bounds__(256)
void transpose_all(TPack p, const float* __restrict__ g1)
{
  __shared__ float tile[32][33];
  const int task = blockIdx.z >> 3;
  const int z = blockIdx.z & 7;
  const int kb = blockIdx.y * 32;
  const int nb = blockIdx.x * 32;
  const float* src = p.src[task] + (long)z * DIM * DQh;
  ushort_t* dst = p.dst[task] + (long)z * DIM * DQh;
  const int tx = threadIdx.x & 31;
  const int ty = threadIdx.x >> 5;
  #pragma unroll
  for (int r = 0; r < 32; r += 8)
    tile[ty + r][tx] = src[(long)(kb + ty + r) * DQh + nb + tx];
  __syncthreads();
  const float gs = (task == 5) ? g1[kb + tx] : 1.0f;
  #pragma unroll
  for (int r = 0; r < 32; r += 8)
    dst[(long)(nb + ty + r) * DIM + kb + tx] = f2bf(tile[tx][ty + r] * gs);
}

// ---------------------------------------------------------------------------
// Merged elementwise casts: 8 tasks; task 4 (E1) scaled by g2[k].
// ---------------------------------------------------------------------------
struct CPack {
  const float* src[8];
  ushort_t* dst[8];
  const float* g2;
};

__global__ __launch_bounds__(256)
void cast_all(CPack p)
{
  const int bid = blockIdx.x;
  int t;
  long base;
  if      (bid < 16384) { t = 0; base = 0; }
  else if (bid < 49152) { t = 1; base = 16384; }
  else if (bid < 50176) { t = 2; base = 49152; }
  else if (bid < 51200) { t = 3; base = 50176; }
  else if (bid < 51712) { t = 4; base = 51200; }
  else if (bid < 52224) { t = 5; base = 51712; }
  else if (bid < 52736) { t = 6; base = 52224; }
  else                  { t = 7; base = 52736; }
  const long i = ((long)(bid - base) * 256 + threadIdx.x) * 4;
  const float4 v = *(const float4*)(p.src[t] + i);
  float4 o = v;
  if (t == 4) {
    const float4 gv = *(const float4*)(p.g2 + (i & 1023));
    o.x *= gv.x; o.y *= gv.y; o.z *= gv.z; o.w *= gv.w;
  }
  ushort4 sv = make_ushort4(f2bf(o.x), f2bf(o.y), f2bf(o.z), f2bf(o.w));
  *(ushort4*)(p.dst[t] + i) = sv;
}

// ---------------------------------------------------------------------------

extern "C" void kernel_launch(void* const* d_in, const int* in_sizes, int n_in,
                              void* d_out, int out_size, void* d_ws, size_t ws_size,
                              hipStream_t stream)
{
  (void)in_sizes; (void)n_in; (void)out_size; (void)ws_size;
  const float* mem = (const float*)d_in[0];
  const float* y0  = (const float*)d_in[1];
  const float* Wq1 = (const float*)d_in[2];
  const float* Wk1 = (const float*)d_in[3];
  const float* Wv1 = (const float*)d_in[4];
  const float* Wo1 = (const float*)d_in[5];
  const float* Wq2 = (const float*)d_in[6];
  const float* Wk2 = (const float*)d_in[7];
  const float* Wv2 = (const float*)d_in[8];
  const float* Wo2 = (const float*)d_in[9];
  const float* E1  = (const float*)d_in[10];
  const float* D1  = (const float*)d_in[11];
  const float* E2  = (const float*)d_in[12];
  const float* D2  = (const float*)d_in[13];
  const float* g1  = (const float*)d_in[14];
  const float* b1  = (const float*)d_in[15];
  const float* g2  = (const float*)d_in[16];
  const float* b2  = (const float*)d_in[17];
  const float* g3  = (const float*)d_in[18];
  const float* b3  = (const float*)d_in[19];

  char* ws = (char*)d_ws;
  const size_t MB = 1ull << 20;
  ushort_t* wkv1  = (ushort_t*)(ws + 0 * MB);
  ushort_t* wq1t  = (ushort_t*)(ws + 4 * MB);
  ushort_t* wkv2  = (ushort_t*)(ws + 6 * MB);
  ushort_t* wq2t  = (ushort_t*)(ws + 10 * MB);   // g1-scaled
  ushort_t* wo1b  = (ushort_t*)(ws + 12 * MB);
  ushort_t* wo2b  = (ushort_t*)(ws + 14 * MB);
  ushort_t* e1b   = (ushort_t*)(ws + 16 * MB);   // g2-scaled
  ushort_t* d1b   = (ushort_t*)(ws + 17 * MB);
  ushort_t* e2b   = (ushort_t*)(ws + 18 * MB);
  ushort_t* d2b   = (ushort_t*)(ws + 19 * MB);
  ushort_t* y0b   = (ushort_t*)(ws + 20 * MB);   // 32 MB
  ushort_t* memb  = (ushort_t*)(ws + 52 * MB);   // 64 MB
  ushort_t* bn2   = (ushort_t*)(ws + 116 * MB);  // 16 MB
  float*    pstat1 = (float*)(ws + 132 * MB);    // 2 MB
  float*    pstat2 = (float*)(ws + 134 * MB);    // 2 MB
  float*    stats1 = (float*)(ws + 136 * MB);    // 128 KB
  float*    stats2 = (float*)(ws + 137 * MB);    // 128 KB
  float*    c1q    = (float*)(ws + 138 * MB);
  float*    c2q    = (float*)(ws + 139 * MB);
  float*    c1e    = (float*)(ws + 140 * MB);
  float*    c2e    = (float*)(ws + 141 * MB);
  ushort_t* kbuf  = (ushort_t*)(ws + 148 * MB);  // 64 MB (s-blocked)
  ushort_t* vbuf  = (ushort_t*)(ws + 212 * MB);  // 64 MB (s-blocked)
  ushort_t* amatT = (ushort_t*)(ws + 276 * MB);  // 4 MB
  ushort_t* attnb = (ushort_t*)(ws + 280 * MB);  // 32 MB
  float*    ybuf  = (float*)(ws + 312 * MB);     // 64 MB (f32 y-chain)
  ushort_t* ybf   = (ushort_t*)(ws + 376 * MB);  // 32 MB (bf16 y)
  ushort_t* hbuf  = (ushort_t*)(ws + 408 * MB);  // 32 MB
  ushort_t* pbuf  = (ushort_t*)(ws + 440 * MB);  // 16 MB (bf16 ktv partials)
  ushort_t* bn1   = attnb;                       // reuse

  // ---- prep (3 dispatches) ----
  CPack cp;
  cp.src[0] = y0;  cp.dst[0] = y0b;
  cp.src[1] = mem; cp.dst[1] = memb;
  cp.src[2] = Wo1; cp.dst[2] = wo1b;
  cp.src[3] = Wo2; cp.dst[3] = wo2b;
  cp.src[4] = E1;  cp.dst[4] = e1b;
  cp.src[5] = D1;  cp.dst[5] = d1b;
  cp.src[6] = E2;  cp.dst[6] = e2b;
  cp.src[7] = D2;  cp.dst[7] = d2b;
  cp.g2 = g2;
  cast_all<<<53248, 256, 0, stream>>>(cp);

  TPack tp;
  tp.src[0] = Wk1; tp.dst[0] = wkv1;
  tp.src[1] = Wv1; tp.dst[1] = wkv1 + (1 << 20);
  tp.src[2] = Wq1; tp.dst[2] = wq1t;
  tp.src[3] = Wk2; tp.dst[3] = wkv2;
  tp.src[4] = Wv2; tp.dst[4] = wkv2 + (1 << 20);
  tp.src[5] = Wq2; tp.dst[5] = wq2t;
  transpose_all<<<dim3(4, 32, 48), 256, 0, stream>>>(tp, g1);

  cvec2<<<384, 256, 0, stream>>>(Wq2, g1, b1, c1q, c2q, E1, g2, b2, c1e, c2e);

  // ---- phase 1: masked self linear-attention ----
  gemm_qkv<<<dim3(16, 128), 256, 0, stream>>>(
      y0b, wkv1, kbuf, vbuf, NB * ST, 2048, DIM, 10, 0b01);
  gemm_ktv<<<dim3(128, 4), 256, 0, stream>>>(kbuf, vbuf, pbuf, ST, 256);
  ktv_reduce<<<1024, 256, 0, stream>>>(pbuf, amatT, 4);
  fused_qa<true, false><<<dim3(8, 128), 256, 0, stream>>>(
      y0b, wq1t, amatT, attnb, nullptr, nullptr, nullptr);
  gemm_bb<ST_YSTAT><<<dim3(8, 128), 256, 0, stream>>>(
      attnb, wo1b, y0, nullptr, nullptr, nullptr, nullptr, nullptr,
      ybf, ybuf, pstat1, NB * ST, DIM, DIM);
  stats_reduce<<<64, 256, 0, stream>>>(pstat1, stats1);

  // ---- phase 2: cross linear-attention ----
  gemm_qkv<<<dim3(16, 256), 256, 0, stream>>>(
      memb, wkv2, kbuf, vbuf, NB * SM, 2048, DIM, 11, 0b01);
  gemm_ktv<<<dim3(128, 4), 256, 0, stream>>>(kbuf, vbuf, pbuf, SM, 512);
  ktv_reduce<<<1024, 256, 0, stream>>>(pbuf, amatT, 4);
  fused_qa<false, true><<<dim3(8, 128), 256, 0, stream>>>(
      ybf, wq2t, amatT, attnb, stats1, c1q, c2q);
  gemm_bb<ST_ZSTAT><<<dim3(8, 128), 256, 0, stream>>>(
      attnb, wo2b, ybuf, stats1, g1, b1, nullptr, nullptr,
      ybf, ybuf, pstat2, NB * ST, DIM, DIM);
  stats_reduce<<<64, 256, 0, stream>>>(pstat2, stats2);

  // ---- phase 3: LFFN ----
  gemm_bb<ST_ABS><<<dim3(4, 128), 256, 0, stream>>>(
      ybf, e1b, nullptr, stats2, nullptr, nullptr, c1e, c2e,
      bn1, nullptr, nullptr, NB * ST, 512, DIM);
  gemm_bb<ST_SWISH><<<dim3(8, 128), 256, 0, stream>>>(
      bn1, d1b, nullptr, nullptr, nullptr, nullptr, nullptr, nullptr,
      hbuf, nullptr, nullptr, NB * ST, DIM, 512);
  gemm_bb<ST_BF16><<<dim3(4, 128), 256, 0, stream>>>(
      hbuf, e2b, nullptr, nullptr, nullptr, nullptr, nullptr, nullptr,
      bn2, nullptr, nullptr, NB * ST, 512, DIM);
  gemm_bb<ST_ZRES><<<dim3(8, 128), 256, 0, stream>>>(
      bn2, d2b, ybuf, stats2, g2, b2, nullptr, nullptr,
      nullptr, ybuf, nullptr, NB * ST, DIM, 512);
  layernorm_k<<<NB * ST, 256, 0, stream>>>(ybuf, g3, b3, (float*)d_out);
}